// Round 3
// baseline (349.784 us; speedup 1.0000x reference)
//
#include <hip/hip_runtime.h>

#define DEVINL static __device__ __forceinline__

constexpr int NUSER = 100000;
constexpr int D     = 128;
constexpr int METAN = 640;
constexpr int NT    = 256;
constexpr int CH    = 4;      // events per worker block (chunk)
constexpr int KP4   = 160;    // W_pred K in float4 (640/4)
constexpr int KR4   = 97;     // RNN combined K in float4 (388/4)
constexpr int NCOPY = 1536;   // copy blocks

struct Params {
  const float *emb_in, *stat, *kg;
  const float *Wihu, *bihu, *Whhu, *bhhu;
  const float *Wihl, *bihl, *Whhl, *bhhl;
  const float *wproj, *bproj, *lng, *lnb, *Wpred, *bpred;
  const float *deltau, *deltal;
  const int *idxu, *idxl, *idxp, *idxk;
  float *emb;        // d_out [N*D]
  float *loss_slot;  // d_out + N*D
  float *WpredT;     // ws [160][256] float4
  float *WrnnT;      // ws [97][256] float4
  float *brnn;       // ws [256]
  float *loss_ev;    // ws [E]
  int *cnt_u, *cnt_w, *cnt_t;
  int *flag_u, *flag_l;
  int E, N, NLOC, NWORK;
};

DEVINL float loadx(const float* p) {
  return __hip_atomic_load(p, __ATOMIC_RELAXED, __HIP_MEMORY_SCOPE_AGENT);
}
DEVINL void storex(float* p, float v) {
  __hip_atomic_store(p, v, __ATOMIC_RELAXED, __HIP_MEMORY_SCOPE_AGENT);
}
DEVINL float dot4(float4 a, float4 b) { return a.x*b.x + a.y*b.y + a.z*b.z + a.w*b.w; }

DEVINL float4 block_sum4(float4 v, float4* s4) {
  #pragma unroll
  for (int o = 32; o; o >>= 1) {
    v.x += __shfl_xor(v.x, o, 64); v.y += __shfl_xor(v.y, o, 64);
    v.z += __shfl_xor(v.z, o, 64); v.w += __shfl_xor(v.w, o, 64);
  }
  if ((threadIdx.x & 63) == 0) s4[threadIdx.x >> 6] = v;
  __syncthreads();
  float4 r;
  r.x = s4[0].x + s4[1].x + s4[2].x + s4[3].x;
  r.y = s4[0].y + s4[1].y + s4[2].y + s4[3].y;
  r.z = s4[0].z + s4[1].z + s4[2].z + s4[3].z;
  r.w = s4[0].w + s4[1].w + s4[2].w + s4[3].w;
  __syncthreads();
  return r;
}

__global__ void k_init(Params p) {
  int tid = blockIdx.x * NT + threadIdx.x;
  int stride = gridDim.x * NT;
  for (int e = tid; e < p.E; e += stride) {
    p.flag_u[p.idxu[e]] = 1;
    p.flag_l[p.idxl[e]] = 1;
  }
  for (int idx = tid; idx < 256 * KP4; idx += stride) {
    int j = idx / KP4, k4 = idx - j * KP4;
    float4 v = *(const float4*)(p.Wpred + (size_t)j * METAN + k4 * 4);
    ((float4*)p.WpredT)[k4 * 256 + j] = v;
  }
  for (int idx = tid; idx < 256 * KR4; idx += stride) {
    int j = idx / KR4, k4 = idx - j * KR4;
    int i = j & 127;
    const float* Wih = (j < 128) ? p.Wihu : p.Wihl;
    const float* Whh = (j < 128) ? p.Whhu : p.Whhl;
    float4 v; float* vp = (float*)&v;
    #pragma unroll
    for (int e = 0; e < 4; ++e) {
      int k = k4 * 4 + e;
      vp[e] = (k < 257) ? Wih[(size_t)i * 257 + k]
            : (k < 385) ? Whh[(size_t)i * 128 + (k - 257)] : 0.f;
    }
    ((float4*)p.WrnnT)[k4 * 256 + j] = v;
  }
  for (int j = tid; j < 256; j += stride)
    p.brnn[j] = (j < 128) ? p.bihu[j] + p.bhhu[j] : p.bihl[j-128] + p.bhhl[j-128];
}

__global__ __launch_bounds__(NT) void k_main(Params p) {
  __shared__ __align__(16) float s_meta[CH][METAN];
  __shared__ __align__(16) float s_xu[CH][388], s_xl[CH][388];
  __shared__ __align__(16) float s_u[CH][D], s_l[CH][D], s_p[CH][D], s_kg[CH][D], s_sil[CH][D];
  __shared__ float4 s_r4[4];
  __shared__ unsigned long long s_redu[4][CH];
  __shared__ int s_ev[8][CH];     // 0:iu 1:il 2:ip 3:A 4:WL 5:B 6:C 7:ik
  __shared__ float s_dd[2][CH];

  const int tid = threadIdx.x, w = tid >> 6, lane = tid & 63;

  if (blockIdx.x >= p.NWORK) {
    size_t g0 = (size_t)(blockIdx.x - p.NWORK) * NT + tid;
    size_t gs = (size_t)NCOPY * NT;
    size_t nf4 = (size_t)p.N * (D / 4);
    const float4* src = (const float4*)p.emb_in;
    float4* dst = (float4*)p.emb;
    for (size_t g = g0; g < nf4; g += gs) {
      int row = (int)(g >> 5);
      int fl = (row < NUSER) ? p.flag_u[row] : p.flag_l[row - NUSER];
      if (!fl) dst[g] = src[g];
    }
    return;
  }

  const int base = blockIdx.x * CH;
  const int nev  = min(CH, p.E - base);

  int iu_[CH], il_[CH], ip_[CH], ik_[CH];
  float du_[CH], dl_[CH];
  #pragma unroll
  for (int e = 0; e < CH; ++e) {
    int t = base + e; bool v = e < nev;
    iu_[e] = v ? p.idxu[t] : -1;
    il_[e] = v ? p.idxl[t] : -1;
    ip_[e] = v ? p.idxp[t] : -1;
    ik_[e] = v ? p.idxk[t] : 0;
    du_[e] = v ? p.deltau[t] : 0.f;
    dl_[e] = v ? p.deltal[t] : 0.f;
  }

  // ---- dependency counts over all events s < base ----
  unsigned long long pk[CH] = {0ull,0ull,0ull,0ull};
  for (int s = tid; s < base; s += NT) {
    int ius = p.idxu[s], ils = p.idxl[s], ips = p.idxp[s];
    #pragma unroll
    for (int e = 0; e < CH; ++e) {
      unsigned long long a  = (ius == iu_[e]);
      unsigned long long wl = (ils == il_[e]);
      unsigned long long b  = (unsigned long long)((ils == il_[e]) + (ips == il_[e]));
      unsigned long long c  = (ils == ip_[e]);
      pk[e] += a | (wl << 16) | (b << 32) | (c << 48);
    }
  }
  #pragma unroll
  for (int o = 32; o; o >>= 1) {
    #pragma unroll
    for (int e = 0; e < CH; ++e) pk[e] += __shfl_xor(pk[e], o, 64);
  }
  if (lane == 0) {
    #pragma unroll
    for (int e = 0; e < CH; ++e) s_redu[w][e] = pk[e];
  }
  __syncthreads();
  #pragma unroll
  for (int e = 0; e < CH; ++e)
    pk[e] = s_redu[0][e] + s_redu[1][e] + s_redu[2][e] + s_redu[3][e];
  __syncthreads();

  // ---- add internal (in-chunk) predecessor counts; detect internal deps ----
  int A_[CH], WL_[CH], B_[CH], C_[CH];
  #pragma unroll
  for (int e = 0; e < CH; ++e) {
    int a  = (int)(pk[e] & 0xffff),        wl = (int)((pk[e] >> 16) & 0xffff);
    int b  = (int)((pk[e] >> 32) & 0xffff), c = (int)((pk[e] >> 48) & 0xffff);
    #pragma unroll
    for (int s2 = 0; s2 < CH; ++s2) if (s2 < e) {
      a  += (iu_[s2] == iu_[e]);
      wl += (il_[s2] == il_[e]);
      b  += (il_[s2] == il_[e]) + (ip_[s2] == il_[e]);
      c  += (il_[s2] == ip_[e]);
    }
    A_[e] = a; WL_[e] = wl; B_[e] = b; C_[e] = c;
  }
  bool internal = false;
  #pragma unroll
  for (int t2 = 1; t2 < CH; ++t2) if (t2 < nev) {
    #pragma unroll
    for (int s2 = 0; s2 < t2; ++s2)
      internal |= (iu_[s2] == iu_[t2]) | (il_[s2] == il_[t2]) |
                  (il_[s2] == ip_[t2]) | (ip_[s2] == il_[t2]);
  }

  if (tid == 0) {
    #pragma unroll
    for (int e = 0; e < CH; ++e) {
      s_ev[0][e] = iu_[e]; s_ev[1][e] = il_[e]; s_ev[2][e] = ip_[e];
      s_ev[3][e] = A_[e];  s_ev[4][e] = WL_[e]; s_ev[5][e] = B_[e];
      s_ev[6][e] = C_[e];  s_ev[7][e] = ik_[e];
      s_dd[0][e] = du_[e]; s_dd[1][e] = dl_[e];
    }
  }
  __syncthreads();

  auto SPIN = [&](int b0, int b1) {
    if (w == 0) {
      int e = b0 + lane;
      bool act = lane < (b1 - b0);
      int iu = 0, il = 0, ip = 0, A = 0, Bc = 0, Cc = 0;
      if (act) {
        iu = s_ev[0][e]; il = s_ev[1][e]; ip = s_ev[2][e];
        A = s_ev[3][e]; Bc = s_ev[5][e]; Cc = s_ev[6][e];
      }
      int guard = 0;
      while (true) {
        bool ok = !act ||
          (__hip_atomic_load(&p.cnt_u[iu], __ATOMIC_RELAXED, __HIP_MEMORY_SCOPE_AGENT) >= A &&
           __hip_atomic_load(&p.cnt_t[il], __ATOMIC_RELAXED, __HIP_MEMORY_SCOPE_AGENT) >= Bc &&
           __hip_atomic_load(&p.cnt_w[ip], __ATOMIC_RELAXED, __HIP_MEMORY_SCOPE_AGENT) >= Cc);
        if (__all(ok)) break;
        if (++guard > (1 << 22)) break;   // safety valve
        __builtin_amdgcn_s_sleep(1);
      }
    }
    __syncthreads();
  };

  auto PROCESS = [&](int b0, int b1) {
    // ---- row loads: wave w handles event w ----
    {
      int e = w;
      if (e >= b0 && e < b1) {
        int iu = s_ev[0][e], ilr = s_ev[1][e] + NUSER, ipr = s_ev[2][e] + NUSER;
        int A = s_ev[3][e], WL = s_ev[4][e], Ck = s_ev[6][e], ik = s_ev[7][e];
        int i0 = lane * 2;
        #pragma unroll
        for (int j = 0; j < 2; ++j) {
          int i = i0 + j;
          s_u[e][i] = A  ? loadx(p.emb + (size_t)iu  * D + i) : p.emb_in[(size_t)iu  * D + i];
          s_l[e][i] = WL ? loadx(p.emb + (size_t)ilr * D + i) : p.emb_in[(size_t)ilr * D + i];
          s_p[e][i] = Ck ? loadx(p.emb + (size_t)ipr * D + i) : p.emb_in[(size_t)ipr * D + i];
        }
        int h2 = lane >> 5, li = (lane & 31) * 4;
        if (h2 == 0) {
          *(float4*)&s_kg[e][li]         = *(const float4*)(p.kg   + (size_t)ik  * D + li);
          *(float4*)&s_meta[e][512 + li] = *(const float4*)(p.stat + (size_t)iu  * D + li);
        } else {
          *(float4*)&s_meta[e][384 + li] = *(const float4*)(p.stat + (size_t)ipr * D + li);
          *(float4*)&s_sil[e][li]        = *(const float4*)(p.stat + (size_t)ilr * D + li);
        }
      }
    }
    __syncthreads();

    // ---- per-event LN + projection + x-vectors (wave-local) ----
    {
      int e = w;
      if (e >= b0 && e < b1) {
        float du = s_dd[0][e], dl = s_dd[1][e];
        float4 xv = (lane < 32) ? *(const float4*)&s_p[e][lane * 4]
                                : *(const float4*)&s_kg[e][(lane - 32) * 4];
        float sm = xv.x + xv.y + xv.z + xv.w;
        #pragma unroll
        for (int o = 32; o; o >>= 1) sm += __shfl_xor(sm, o, 64);
        float mu = sm * (1.f / 256.f);
        float4 d = make_float4(xv.x - mu, xv.y - mu, xv.z - mu, xv.w - mu);
        float vs = d.x*d.x + d.y*d.y + d.z*d.z + d.w*d.w;
        #pragma unroll
        for (int o = 32; o; o >>= 1) vs += __shfl_xor(vs, o, 64);
        float rstd = rsqrtf(vs * (1.f / 256.f) + 1e-5f);
        int idx = lane * 4;
        float4 g  = *(const float4*)&p.lng[idx];
        float4 bb = *(const float4*)&p.lnb[idx];
        *(float4*)&s_meta[e][128 + idx] = make_float4(
          d.x*rstd*g.x + bb.x, d.y*rstd*g.y + bb.y,
          d.z*rstd*g.z + bb.z, d.w*rstd*g.w + bb.w);

        int i0 = lane * 2;
        #pragma unroll
        for (int j = 0; j < 2; ++j) {
          int i = i0 + j;
          float uu = s_u[e][i], ll = s_l[e][i], kk = s_kg[e][i];
          s_meta[e][i] = uu * (1.f + p.wproj[i] * du + p.bproj[i]);
          s_xu[e][i] = ll;        s_xl[e][i] = uu;
          s_xu[e][128 + i] = kk;  s_xl[e][128 + i] = kk;
          s_xu[e][257 + i] = uu;  s_xl[e][257 + i] = ll;
        }
        if (lane == 0) {
          s_xu[e][256] = du; s_xl[e][256] = dl;
          s_xu[e][385] = s_xu[e][386] = s_xu[e][387] = 0.f;
          s_xl[e][385] = s_xl[e][386] = s_xl[e][387] = 0.f;
        }
      }
    }
    __syncthreads();

    // ---- batched pred matvec: thread j, 4 events ----
    const float4* m40 = (const float4*)&s_meta[0][0];
    const float4* m41 = (const float4*)&s_meta[1][0];
    const float4* m42 = (const float4*)&s_meta[2][0];
    const float4* m43 = (const float4*)&s_meta[3][0];
    float pa0 = 0.f, pa1 = 0.f, pa2 = 0.f, pa3 = 0.f;
    const float4* wp = (const float4*)p.WpredT + tid;
    #pragma unroll 8
    for (int k4 = 0; k4 < KP4; ++k4) {
      float4 wv = wp[k4 * 256];
      pa0 += dot4(wv, m40[k4]); pa1 += dot4(wv, m41[k4]);
      pa2 += dot4(wv, m42[k4]); pa3 += dot4(wv, m43[k4]);
    }
    float bp = p.bpred[tid];
    float4 ep2;
    {
      float tg0 = (tid < 128) ? s_l[0][tid] : s_sil[0][tid - 128];
      float tg1 = (tid < 128) ? s_l[1][tid] : s_sil[1][tid - 128];
      float tg2 = (tid < 128) ? s_l[2][tid] : s_sil[2][tid - 128];
      float tg3 = (tid < 128) ? s_l[3][tid] : s_sil[3][tid - 128];
      float e0 = pa0 + bp - tg0, e1 = pa1 + bp - tg1;
      float e2 = pa2 + bp - tg2, e3 = pa3 + bp - tg3;
      ep2 = make_float4(e0*e0, e1*e1, e2*e2, e3*e3);
    }
    float4 LP = block_sum4(ep2, s_r4);

    // ---- batched RNN matvec ----
    const float4* xb0 = (const float4*)((tid < 128) ? s_xu[0] : s_xl[0]);
    const float4* xb1 = (const float4*)((tid < 128) ? s_xu[1] : s_xl[1]);
    const float4* xb2 = (const float4*)((tid < 128) ? s_xu[2] : s_xl[2]);
    const float4* xb3 = (const float4*)((tid < 128) ? s_xu[3] : s_xl[3]);
    float ra0 = 0.f, ra1 = 0.f, ra2 = 0.f, ra3 = 0.f;
    const float4* wr = (const float4*)p.WrnnT + tid;
    #pragma unroll 8
    for (int k4 = 0; k4 < KR4; ++k4) {
      float4 wv = wr[k4 * 256];
      ra0 += dot4(wv, xb0[k4]); ra1 += dot4(wv, xb1[k4]);
      ra2 += dot4(wv, xb2[k4]); ra3 += dot4(wv, xb3[k4]);
    }
    float brn = p.brnn[tid];
    float h0 = tanhf(ra0 + brn), h1 = tanhf(ra1 + brn);
    float h2v = tanhf(ra2 + brn), h3 = tanhf(ra3 + brn);

    float4 hh = make_float4(h0*h0, h1*h1, h2v*h2v, h3*h3);
    float4 z4 = make_float4(0.f, 0.f, 0.f, 0.f);
    float4 SU = block_sum4((tid < 128) ? hh : z4, s_r4);
    float4 SL = block_sum4((tid < 128) ? z4 : hh, s_r4);
    float s0 = (tid < 128) ? SU.x : SL.x, s1 = (tid < 128) ? SU.y : SL.y;
    float s2 = (tid < 128) ? SU.z : SL.z, s3 = (tid < 128) ? SU.w : SL.w;
    float n0 = h0 / fmaxf(sqrtf(s0), 1e-12f), n1 = h1 / fmaxf(sqrtf(s1), 1e-12f);
    float n2 = h2v / fmaxf(sqrtf(s2), 1e-12f), n3 = h3 / fmaxf(sqrtf(s3), 1e-12f);
    float o0 = (tid < 128) ? s_u[0][tid] : s_l[0][tid - 128];
    float o1 = (tid < 128) ? s_u[1][tid] : s_l[1][tid - 128];
    float o2 = (tid < 128) ? s_u[2][tid] : s_l[2][tid - 128];
    float o3 = (tid < 128) ? s_u[3][tid] : s_l[3][tid - 128];
    float q0 = n0 - o0, q1 = n1 - o1, q2 = n2 - o2, q3 = n3 - o3;
    float4 LE = block_sum4(make_float4(q0*q0, q1*q1, q2*q2, q3*q3), s_r4);

    if (tid >= b0 && tid < b1) {
      float lp = (tid == 0) ? LP.x : (tid == 1) ? LP.y : (tid == 2) ? LP.z : LP.w;
      float le = (tid == 0) ? LE.x : (tid == 1) ? LE.y : (tid == 2) ? LE.z : LE.w;
      p.loss_ev[base + tid] = lp * (1.f / 256.f) + le * (1.f / 128.f);
    }

    float nv[CH] = {n0, n1, n2, n3};
    #pragma unroll
    for (int e = 0; e < CH; ++e) if (e >= b0 && e < b1) {
      if (tid < 128) storex(p.emb + (size_t)s_ev[0][e] * D + tid, nv[e]);
      else           storex(p.emb + ((size_t)s_ev[1][e] + NUSER) * D + (tid - 128), nv[e]);
    }
    __syncthreads();

    if (tid >= b0 && tid < b1) {
      __threadfence();
      atomicAdd(&p.cnt_u[s_ev[0][tid]], 1);
      atomicAdd(&p.cnt_t[s_ev[1][tid]], 1);
      atomicAdd(&p.cnt_w[s_ev[1][tid]], 1);
      atomicAdd(&p.cnt_t[s_ev[2][tid]], 1);
    }
  };

  if (!internal) {
    SPIN(0, nev);
    PROCESS(0, nev);
  } else {
    for (int e = 0; e < nev; ++e) {
      SPIN(e, e + 1);
      PROCESS(e, e + 1);
    }
  }
}

__global__ void k_fin(Params p) {
  __shared__ float4 s_r4[4];
  float v = 0.f;
  for (int i = threadIdx.x; i < p.E; i += NT) v += p.loss_ev[i];
  float4 r = block_sum4(make_float4(v, 0.f, 0.f, 0.f), s_r4);
  if (threadIdx.x == 0) p.loss_slot[0] = r.x;
}

extern "C" void kernel_launch(void* const* d_in, const int* in_sizes, int n_in,
                              void* d_out, int out_size, void* d_ws, size_t ws_size,
                              hipStream_t stream) {
  Params p;
  p.emb_in = (const float*)d_in[0];
  p.stat   = (const float*)d_in[1];
  p.kg     = (const float*)d_in[2];
  p.Wihu = (const float*)d_in[3];   p.bihu = (const float*)d_in[4];
  p.Whhu = (const float*)d_in[5];   p.bhhu = (const float*)d_in[6];
  p.Wihl = (const float*)d_in[7];   p.bihl = (const float*)d_in[8];
  p.Whhl = (const float*)d_in[9];   p.bhhl = (const float*)d_in[10];
  p.wproj = (const float*)d_in[11]; p.bproj = (const float*)d_in[12];
  p.lng  = (const float*)d_in[13];  p.lnb  = (const float*)d_in[14];
  p.Wpred = (const float*)d_in[15]; p.bpred = (const float*)d_in[16];
  p.deltau = (const float*)d_in[17];
  p.deltal = (const float*)d_in[18];
  p.idxu = (const int*)d_in[19];
  p.idxl = (const int*)d_in[20];
  p.idxp = (const int*)d_in[21];
  p.idxk = (const int*)d_in[22];

  p.E    = in_sizes[17];
  p.N    = in_sizes[0] / D;
  p.NLOC = p.N - NUSER;
  p.NWORK = (p.E + CH - 1) / CH;

  p.emb       = (float*)d_out;
  p.loss_slot = (float*)d_out + (size_t)p.N * D;

  char* ws = (char*)d_ws;
  size_t off = 0;
  auto take = [&](size_t bytes) {
    void* r = ws + off;
    off += (bytes + 255) & ~(size_t)255;
    return r;
  };
  p.WpredT  = (float*)take((size_t)KP4 * 256 * 16);
  p.WrnnT   = (float*)take((size_t)KR4 * 256 * 16);
  p.brnn    = (float*)take(256 * 4);
  p.loss_ev = (float*)take((size_t)p.E * 4);
  size_t z0 = off;
  p.cnt_u   = (int*)take((size_t)NUSER * 4);
  p.cnt_w   = (int*)take((size_t)p.NLOC * 4);
  p.cnt_t   = (int*)take((size_t)p.NLOC * 4);
  p.flag_u  = (int*)take((size_t)NUSER * 4);
  p.flag_l  = (int*)take((size_t)p.NLOC * 4);
  size_t zbytes = off - z0;

  hipMemsetAsync(ws + z0, 0, zbytes, stream);
  hipLaunchKernelGGL(k_init, dim3(512), dim3(NT), 0, stream, p);
  hipLaunchKernelGGL(k_main, dim3(p.NWORK + NCOPY), dim3(NT), 0, stream, p);
  hipLaunchKernelGGL(k_fin,  dim3(1),   dim3(NT), 0, stream, p);
}

// Round 4
// 336.321 us; speedup vs baseline: 1.0400x; 1.0400x over previous
//
#include <hip/hip_runtime.h>

#define DEVINL static __device__ __forceinline__

constexpr int NUSER = 100000;
constexpr int D     = 128;
constexpr int METAN = 640;
constexpr int NT    = 256;
constexpr int CH    = 4;      // events per worker block (chunk)
constexpr int KP4   = 160;    // W_pred K in float4 (640/4)
constexpr int KR4   = 96;     // RNN combined K in float4 (384/4), segment-aligned
constexpr int TROWS = 256;    // rows per copy ticket

struct Params {
  const float *emb_in, *stat, *kg;
  const float *Wihu, *bihu, *Whhu, *bhhu;
  const float *Wihl, *bihl, *Whhl, *bhhl;
  const float *wproj, *bproj, *lng, *lnb, *Wpred, *bpred;
  const float *deltau, *deltal;
  const int *idxu, *idxl, *idxp, *idxk;
  float *emb;        // d_out [N*D]
  float *loss_slot;  // d_out + N*D
  float *WpredT;     // ws [160][256] float4
  float *WrnnT;      // ws [96][256] float4 (k: [other(128)|kg(128)|own(128)])
  float *brnn;       // ws [256]  (bih+bhh)
  float *wcol;       // ws [256]  (Wih[:,256] = delta column)
  float *loss_ev;    // ws [E]
  int *cnt_u, *cnt_w, *cnt_t;
  int *flag_u, *flag_l;
  int *ticket;
  int E, N, NLOC, NWORK;
};

DEVINL float loadx(const float* p) {
  return __hip_atomic_load(p, __ATOMIC_RELAXED, __HIP_MEMORY_SCOPE_AGENT);
}
DEVINL void storex(float* p, float v) {
  __hip_atomic_store(p, v, __ATOMIC_RELAXED, __HIP_MEMORY_SCOPE_AGENT);
}
DEVINL float dot4(float4 a, float4 b) { return a.x*b.x + a.y*b.y + a.z*b.z + a.w*b.w; }

DEVINL float4 block_sum4(float4 v, float4* s4) {
  #pragma unroll
  for (int o = 32; o; o >>= 1) {
    v.x += __shfl_xor(v.x, o, 64); v.y += __shfl_xor(v.y, o, 64);
    v.z += __shfl_xor(v.z, o, 64); v.w += __shfl_xor(v.w, o, 64);
  }
  if ((threadIdx.x & 63) == 0) s4[threadIdx.x >> 6] = v;
  __syncthreads();
  float4 r;
  r.x = s4[0].x + s4[1].x + s4[2].x + s4[3].x;
  r.y = s4[0].y + s4[1].y + s4[2].y + s4[3].y;
  r.z = s4[0].z + s4[1].z + s4[2].z + s4[3].z;
  r.w = s4[0].w + s4[1].w + s4[2].w + s4[3].w;
  __syncthreads();
  return r;
}

// per-wave-pair sums: returns {sum over waves 0-1 (tid<128), sum over waves 2-3}
DEVINL void half_sum4(float4 v, float4* s4, float4* lo, float4* hi) {
  #pragma unroll
  for (int o = 32; o; o >>= 1) {
    v.x += __shfl_xor(v.x, o, 64); v.y += __shfl_xor(v.y, o, 64);
    v.z += __shfl_xor(v.z, o, 64); v.w += __shfl_xor(v.w, o, 64);
  }
  if ((threadIdx.x & 63) == 0) s4[threadIdx.x >> 6] = v;
  __syncthreads();
  lo->x = s4[0].x + s4[1].x; lo->y = s4[0].y + s4[1].y;
  lo->z = s4[0].z + s4[1].z; lo->w = s4[0].w + s4[1].w;
  hi->x = s4[2].x + s4[3].x; hi->y = s4[2].y + s4[3].y;
  hi->z = s4[2].z + s4[3].z; hi->w = s4[2].w + s4[3].w;
  __syncthreads();
}

__global__ void k_init(Params p) {
  int tid = blockIdx.x * NT + threadIdx.x;
  int stride = gridDim.x * NT;
  for (int e = tid; e < p.E; e += stride) {
    p.flag_u[p.idxu[e]] = 1;
    p.flag_l[p.idxl[e]] = 1;
  }
  for (int idx = tid; idx < 256 * KP4; idx += stride) {
    int j = idx / KP4, k4 = idx - j * KP4;
    float4 v = *(const float4*)(p.Wpred + (size_t)j * METAN + k4 * 4);
    ((float4*)p.WpredT)[k4 * 256 + j] = v;
  }
  // WrnnT: k<256 -> Wih[i,k]; 256<=k<384 -> Whh[i,k-256]
  for (int idx = tid; idx < 256 * KR4; idx += stride) {
    int j = idx / KR4, k4 = idx - j * KR4;
    int i = j & 127;
    const float* Wih = (j < 128) ? p.Wihu : p.Wihl;
    const float* Whh = (j < 128) ? p.Whhu : p.Whhl;
    float4 v; float* vp = (float*)&v;
    #pragma unroll
    for (int e = 0; e < 4; ++e) {
      int k = k4 * 4 + e;
      vp[e] = (k < 256) ? Wih[(size_t)i * 257 + k] : Whh[(size_t)i * 128 + (k - 256)];
    }
    ((float4*)p.WrnnT)[k4 * 256 + j] = v;
  }
  for (int j = tid; j < 256; j += stride) {
    int i = j & 127;
    p.brnn[j] = (j < 128) ? p.bihu[i] + p.bhhu[i] : p.bihl[i] + p.bhhl[i];
    p.wcol[j] = (j < 128) ? p.Wihu[(size_t)i * 257 + 256] : p.Wihl[(size_t)i * 257 + 256];
  }
}

__global__ __launch_bounds__(NT) void k_main(Params p) {
  __shared__ __align__(16) float s_meta[CH][METAN];
  __shared__ __align__(16) float s_u[CH][D], s_l[CH][D], s_p[CH][D], s_kg[CH][D], s_sil[CH][D];
  __shared__ float4 s_r4[4];
  __shared__ unsigned long long s_redu[4][CH];
  __shared__ int s_ev[8][CH];     // 0:iu 1:il 2:ip 3:A 4:WL 5:B 6:C 7:ik
  __shared__ float s_dd[2][CH];
  __shared__ int s_tile;

  const int tid = threadIdx.x, w = tid >> 6, lane = tid & 63;

  const int base = blockIdx.x * CH;
  const int nev  = min(CH, p.E - base);

  if (nev > 0) {
    int iu_[CH], il_[CH], ip_[CH], ik_[CH];
    float du_[CH], dl_[CH];
    #pragma unroll
    for (int e = 0; e < CH; ++e) {
      int t = base + e; bool v = e < nev;
      iu_[e] = v ? p.idxu[t] : -1;
      il_[e] = v ? p.idxl[t] : -1;
      ip_[e] = v ? p.idxp[t] : -1;
      ik_[e] = v ? p.idxk[t] : 0;
      du_[e] = v ? p.deltau[t] : 0.f;
      dl_[e] = v ? p.deltal[t] : 0.f;
    }

    // ---- dependency counts over events s < base ----
    unsigned long long pk[CH] = {0ull,0ull,0ull,0ull};
    for (int s = tid; s < base; s += NT) {
      int ius = p.idxu[s], ils = p.idxl[s], ips = p.idxp[s];
      #pragma unroll
      for (int e = 0; e < CH; ++e) {
        unsigned long long a  = (ius == iu_[e]);
        unsigned long long wl = (ils == il_[e]);
        unsigned long long b  = (unsigned long long)((ils == il_[e]) + (ips == il_[e]));
        unsigned long long c  = (ils == ip_[e]);
        pk[e] += a | (wl << 16) | (b << 32) | (c << 48);
      }
    }
    #pragma unroll
    for (int o = 32; o; o >>= 1) {
      #pragma unroll
      for (int e = 0; e < CH; ++e) pk[e] += __shfl_xor(pk[e], o, 64);
    }
    if (lane == 0) {
      #pragma unroll
      for (int e = 0; e < CH; ++e) s_redu[w][e] = pk[e];
    }
    __syncthreads();
    #pragma unroll
    for (int e = 0; e < CH; ++e)
      pk[e] = s_redu[0][e] + s_redu[1][e] + s_redu[2][e] + s_redu[3][e];
    __syncthreads();

    int A_[CH], WL_[CH], B_[CH], C_[CH];
    #pragma unroll
    for (int e = 0; e < CH; ++e) {
      int a  = (int)(pk[e] & 0xffff),        wl = (int)((pk[e] >> 16) & 0xffff);
      int b  = (int)((pk[e] >> 32) & 0xffff), c = (int)((pk[e] >> 48) & 0xffff);
      #pragma unroll
      for (int s2 = 0; s2 < CH; ++s2) if (s2 < e) {
        a  += (iu_[s2] == iu_[e]);
        wl += (il_[s2] == il_[e]);
        b  += (il_[s2] == il_[e]) + (ip_[s2] == il_[e]);
        c  += (il_[s2] == ip_[e]);
      }
      A_[e] = a; WL_[e] = wl; B_[e] = b; C_[e] = c;
    }
    bool internal = false;
    #pragma unroll
    for (int t2 = 1; t2 < CH; ++t2) if (t2 < nev) {
      #pragma unroll
      for (int s2 = 0; s2 < t2; ++s2)
        internal |= (iu_[s2] == iu_[t2]) | (il_[s2] == il_[t2]) |
                    (il_[s2] == ip_[t2]) | (ip_[s2] == il_[t2]);
    }

    if (tid == 0) {
      #pragma unroll
      for (int e = 0; e < CH; ++e) {
        s_ev[0][e] = iu_[e]; s_ev[1][e] = il_[e]; s_ev[2][e] = ip_[e];
        s_ev[3][e] = A_[e];  s_ev[4][e] = WL_[e]; s_ev[5][e] = B_[e];
        s_ev[6][e] = C_[e];  s_ev[7][e] = ik_[e];
        s_dd[0][e] = du_[e]; s_dd[1][e] = dl_[e];
      }
    }
    __syncthreads();

    auto SPIN = [&](int b0, int b1) {
      if (w == 0) {
        int e = b0 + lane;
        bool act = lane < (b1 - b0);
        int iu = 0, il = 0, ip = 0, A = 0, Bc = 0, Cc = 0;
        if (act) {
          iu = s_ev[0][e]; il = s_ev[1][e]; ip = s_ev[2][e];
          A = s_ev[3][e]; Bc = s_ev[5][e]; Cc = s_ev[6][e];
        }
        int guard = 0;
        while (true) {
          bool ok = !act ||
            (__hip_atomic_load(&p.cnt_u[iu], __ATOMIC_RELAXED, __HIP_MEMORY_SCOPE_AGENT) >= A &&
             __hip_atomic_load(&p.cnt_t[il], __ATOMIC_RELAXED, __HIP_MEMORY_SCOPE_AGENT) >= Bc &&
             __hip_atomic_load(&p.cnt_w[ip], __ATOMIC_RELAXED, __HIP_MEMORY_SCOPE_AGENT) >= Cc);
          if (__all(ok)) break;
          if (++guard > (1 << 22)) break;   // safety valve
          __builtin_amdgcn_s_sleep(1);
        }
      }
      __syncthreads();
    };

    auto PROCESS = [&](int b0, int b1) {
      // ---- row loads: wave w handles event w ----
      {
        int e = w;
        if (e >= b0 && e < b1) {
          int iu = s_ev[0][e], ilr = s_ev[1][e] + NUSER, ipr = s_ev[2][e] + NUSER;
          int A = s_ev[3][e], WL = s_ev[4][e], Ck = s_ev[6][e], ik = s_ev[7][e];
          int i0 = lane * 2;
          #pragma unroll
          for (int j = 0; j < 2; ++j) {
            int i = i0 + j;
            s_u[e][i] = A  ? loadx(p.emb + (size_t)iu  * D + i) : p.emb_in[(size_t)iu  * D + i];
            s_l[e][i] = WL ? loadx(p.emb + (size_t)ilr * D + i) : p.emb_in[(size_t)ilr * D + i];
            s_p[e][i] = Ck ? loadx(p.emb + (size_t)ipr * D + i) : p.emb_in[(size_t)ipr * D + i];
          }
          int h2 = lane >> 5, li = (lane & 31) * 4;
          if (h2 == 0) {
            *(float4*)&s_kg[e][li]         = *(const float4*)(p.kg   + (size_t)ik  * D + li);
            *(float4*)&s_meta[e][512 + li] = *(const float4*)(p.stat + (size_t)iu  * D + li);
          } else {
            *(float4*)&s_meta[e][384 + li] = *(const float4*)(p.stat + (size_t)ipr * D + li);
            *(float4*)&s_sil[e][li]        = *(const float4*)(p.stat + (size_t)ilr * D + li);
          }
        }
      }
      __syncthreads();

      // ---- per-event LN + projection (wave-local) ----
      {
        int e = w;
        if (e >= b0 && e < b1) {
          float du = s_dd[0][e];
          float4 xv = (lane < 32) ? *(const float4*)&s_p[e][lane * 4]
                                  : *(const float4*)&s_kg[e][(lane - 32) * 4];
          float sm = xv.x + xv.y + xv.z + xv.w;
          #pragma unroll
          for (int o = 32; o; o >>= 1) sm += __shfl_xor(sm, o, 64);
          float mu = sm * (1.f / 256.f);
          float4 d = make_float4(xv.x - mu, xv.y - mu, xv.z - mu, xv.w - mu);
          float vs = d.x*d.x + d.y*d.y + d.z*d.z + d.w*d.w;
          #pragma unroll
          for (int o = 32; o; o >>= 1) vs += __shfl_xor(vs, o, 64);
          float rstd = rsqrtf(vs * (1.f / 256.f) + 1e-5f);
          int idx = lane * 4;
          float4 g  = *(const float4*)&p.lng[idx];
          float4 bb = *(const float4*)&p.lnb[idx];
          *(float4*)&s_meta[e][128 + idx] = make_float4(
            d.x*rstd*g.x + bb.x, d.y*rstd*g.y + bb.y,
            d.z*rstd*g.z + bb.z, d.w*rstd*g.w + bb.w);

          int i0 = lane * 2;
          #pragma unroll
          for (int j = 0; j < 2; ++j) {
            int i = i0 + j;
            s_meta[e][i] = s_u[e][i] * (1.f + p.wproj[i] * du + p.bproj[i]);
          }
        }
      }
      __syncthreads();

      // ---- batched pred matvec ----
      const float4* m40 = (const float4*)&s_meta[0][0];
      const float4* m41 = (const float4*)&s_meta[1][0];
      const float4* m42 = (const float4*)&s_meta[2][0];
      const float4* m43 = (const float4*)&s_meta[3][0];
      float pa0 = 0.f, pa1 = 0.f, pa2 = 0.f, pa3 = 0.f;
      const float4* wp = (const float4*)p.WpredT + tid;
      #pragma unroll 8
      for (int k4 = 0; k4 < KP4; ++k4) {
        float4 wv = wp[k4 * 256];
        pa0 += dot4(wv, m40[k4]); pa1 += dot4(wv, m41[k4]);
        pa2 += dot4(wv, m42[k4]); pa3 += dot4(wv, m43[k4]);
      }
      float bp = p.bpred[tid];
      float4 ep2;
      {
        float tg0 = (tid < 128) ? s_l[0][tid] : s_sil[0][tid - 128];
        float tg1 = (tid < 128) ? s_l[1][tid] : s_sil[1][tid - 128];
        float tg2 = (tid < 128) ? s_l[2][tid] : s_sil[2][tid - 128];
        float tg3 = (tid < 128) ? s_l[3][tid] : s_sil[3][tid - 128];
        float e0 = pa0 + bp - tg0, e1 = pa1 + bp - tg1;
        float e2 = pa2 + bp - tg2, e3 = pa3 + bp - tg3;
        ep2 = make_float4(e0*e0, e1*e1, e2*e2, e3*e3);
      }
      float4 LP = block_sum4(ep2, s_r4);

      // ---- batched RNN matvec, segment-aligned x from s_u/s_l/s_kg ----
      const bool uc = (tid < 128);
      const float4* xo0 = (const float4*)(uc ? s_l[0] : s_u[0]);
      const float4* xo1 = (const float4*)(uc ? s_l[1] : s_u[1]);
      const float4* xo2 = (const float4*)(uc ? s_l[2] : s_u[2]);
      const float4* xo3 = (const float4*)(uc ? s_l[3] : s_u[3]);
      const float4* xk0 = (const float4*)s_kg[0];
      const float4* xk1 = (const float4*)s_kg[1];
      const float4* xk2 = (const float4*)s_kg[2];
      const float4* xk3 = (const float4*)s_kg[3];
      const float4* xs0 = (const float4*)(uc ? s_u[0] : s_l[0]);
      const float4* xs1 = (const float4*)(uc ? s_u[1] : s_l[1]);
      const float4* xs2 = (const float4*)(uc ? s_u[2] : s_l[2]);
      const float4* xs3 = (const float4*)(uc ? s_u[3] : s_l[3]);
      float ra0 = 0.f, ra1 = 0.f, ra2 = 0.f, ra3 = 0.f;
      const float4* wr = (const float4*)p.WrnnT + tid;
      #pragma unroll 8
      for (int k4 = 0; k4 < 32; ++k4) {
        float4 wv = wr[k4 * 256];
        ra0 += dot4(wv, xo0[k4]); ra1 += dot4(wv, xo1[k4]);
        ra2 += dot4(wv, xo2[k4]); ra3 += dot4(wv, xo3[k4]);
      }
      #pragma unroll 8
      for (int k4 = 32; k4 < 64; ++k4) {
        float4 wv = wr[k4 * 256];
        ra0 += dot4(wv, xk0[k4-32]); ra1 += dot4(wv, xk1[k4-32]);
        ra2 += dot4(wv, xk2[k4-32]); ra3 += dot4(wv, xk3[k4-32]);
      }
      #pragma unroll 8
      for (int k4 = 64; k4 < 96; ++k4) {
        float4 wv = wr[k4 * 256];
        ra0 += dot4(wv, xs0[k4-64]); ra1 += dot4(wv, xs1[k4-64]);
        ra2 += dot4(wv, xs2[k4-64]); ra3 += dot4(wv, xs3[k4-64]);
      }
      float brn = p.brnn[tid], wcv = p.wcol[tid];
      float d0 = uc ? s_dd[0][0] : s_dd[1][0];
      float d1 = uc ? s_dd[0][1] : s_dd[1][1];
      float d2 = uc ? s_dd[0][2] : s_dd[1][2];
      float d3 = uc ? s_dd[0][3] : s_dd[1][3];
      float h0 = tanhf(ra0 + brn + wcv * d0), h1 = tanhf(ra1 + brn + wcv * d1);
      float h2v = tanhf(ra2 + brn + wcv * d2), h3 = tanhf(ra3 + brn + wcv * d3);

      // ---- L2-normalize halves (one reduction via wave-pair sums) ----
      float4 SU, SL;
      half_sum4(make_float4(h0*h0, h1*h1, h2v*h2v, h3*h3), s_r4, &SU, &SL);
      float s0 = uc ? SU.x : SL.x, s1 = uc ? SU.y : SL.y;
      float s2 = uc ? SU.z : SL.z, s3 = uc ? SU.w : SL.w;
      float n0 = h0 / fmaxf(sqrtf(s0), 1e-12f), n1 = h1 / fmaxf(sqrtf(s1), 1e-12f);
      float n2 = h2v / fmaxf(sqrtf(s2), 1e-12f), n3 = h3 / fmaxf(sqrtf(s3), 1e-12f);
      float o0 = uc ? s_u[0][tid] : s_l[0][tid - 128];
      float o1 = uc ? s_u[1][tid] : s_l[1][tid - 128];
      float o2 = uc ? s_u[2][tid] : s_l[2][tid - 128];
      float o3 = uc ? s_u[3][tid] : s_l[3][tid - 128];
      float q0 = n0 - o0, q1 = n1 - o1, q2 = n2 - o2, q3 = n3 - o3;
      float4 LE = block_sum4(make_float4(q0*q0, q1*q1, q2*q2, q3*q3), s_r4);

      if (tid >= b0 && tid < b1) {
        float lp = (tid == 0) ? LP.x : (tid == 1) ? LP.y : (tid == 2) ? LP.z : LP.w;
        float le = (tid == 0) ? LE.x : (tid == 1) ? LE.y : (tid == 2) ? LE.z : LE.w;
        p.loss_ev[base + tid] = lp * (1.f / 256.f) + le * (1.f / 128.f);
      }

      float nv[CH] = {n0, n1, n2, n3};
      #pragma unroll
      for (int e = 0; e < CH; ++e) if (e >= b0 && e < b1) {
        if (tid < 128) storex(p.emb + (size_t)s_ev[0][e] * D + tid, nv[e]);
        else           storex(p.emb + ((size_t)s_ev[1][e] + NUSER) * D + (tid - 128), nv[e]);
      }
      __syncthreads();

      if (tid >= b0 && tid < b1) {
        __threadfence();
        atomicAdd(&p.cnt_u[s_ev[0][tid]], 1);
        atomicAdd(&p.cnt_t[s_ev[1][tid]], 1);
        atomicAdd(&p.cnt_w[s_ev[1][tid]], 1);
        atomicAdd(&p.cnt_t[s_ev[2][tid]], 1);
      }
    };

    if (!internal) {
      SPIN(0, nev);
      PROCESS(0, nev);
    } else {
      for (int e = 0; e < nev; ++e) {
        SPIN(e, e + 1);
        PROCESS(e, e + 1);
      }
    }
  }

  // ---- copy phase: ticket-based, overlapped with other blocks' event work ----
  const int ntiles = (p.N + TROWS - 1) / TROWS;
  const float4* src = (const float4*)p.emb_in;
  float4* dst = (float4*)p.emb;
  for (;;) {
    if (tid == 0) s_tile = atomicAdd(p.ticket, 1);
    __syncthreads();
    int tile = s_tile;
    __syncthreads();
    if (tile >= ntiles) break;
    int r0 = tile * TROWS;
    int nrow = min(TROWS, p.N - r0);
    for (int idx = tid; idx < nrow * 32; idx += NT) {
      int row = r0 + (idx >> 5);
      int fl = (row < NUSER) ? p.flag_u[row] : p.flag_l[row - NUSER];
      if (!fl) {
        size_t g = (size_t)row * 32 + (idx & 31);
        dst[g] = src[g];
      }
    }
  }
}

__global__ void k_fin(Params p) {
  __shared__ float4 s_r4[4];
  float v = 0.f;
  for (int i = threadIdx.x; i < p.E; i += NT) v += p.loss_ev[i];
  float4 r = block_sum4(make_float4(v, 0.f, 0.f, 0.f), s_r4);
  if (threadIdx.x == 0) p.loss_slot[0] = r.x;
}

extern "C" void kernel_launch(void* const* d_in, const int* in_sizes, int n_in,
                              void* d_out, int out_size, void* d_ws, size_t ws_size,
                              hipStream_t stream) {
  Params p;
  p.emb_in = (const float*)d_in[0];
  p.stat   = (const float*)d_in[1];
  p.kg     = (const float*)d_in[2];
  p.Wihu = (const float*)d_in[3];   p.bihu = (const float*)d_in[4];
  p.Whhu = (const float*)d_in[5];   p.bhhu = (const float*)d_in[6];
  p.Wihl = (const float*)d_in[7];   p.bihl = (const float*)d_in[8];
  p.Whhl = (const float*)d_in[9];   p.bhhl = (const float*)d_in[10];
  p.wproj = (const float*)d_in[11]; p.bproj = (const float*)d_in[12];
  p.lng  = (const float*)d_in[13];  p.lnb  = (const float*)d_in[14];
  p.Wpred = (const float*)d_in[15]; p.bpred = (const float*)d_in[16];
  p.deltau = (const float*)d_in[17];
  p.deltal = (const float*)d_in[18];
  p.idxu = (const int*)d_in[19];
  p.idxl = (const int*)d_in[20];
  p.idxp = (const int*)d_in[21];
  p.idxk = (const int*)d_in[22];

  p.E    = in_sizes[17];
  p.N    = in_sizes[0] / D;
  p.NLOC = p.N - NUSER;
  p.NWORK = (p.E + CH - 1) / CH;

  p.emb       = (float*)d_out;
  p.loss_slot = (float*)d_out + (size_t)p.N * D;

  char* ws = (char*)d_ws;
  size_t off = 0;
  auto take = [&](size_t bytes) {
    void* r = ws + off;
    off += (bytes + 255) & ~(size_t)255;
    return r;
  };
  p.WpredT  = (float*)take((size_t)KP4 * 256 * 16);
  p.WrnnT   = (float*)take((size_t)KR4 * 256 * 16);
  p.brnn    = (float*)take(256 * 4);
  p.wcol    = (float*)take(256 * 4);
  p.loss_ev = (float*)take((size_t)p.E * 4);
  size_t z0 = off;
  p.cnt_u   = (int*)take((size_t)NUSER * 4);
  p.cnt_w   = (int*)take((size_t)p.NLOC * 4);
  p.cnt_t   = (int*)take((size_t)p.NLOC * 4);
  p.flag_u  = (int*)take((size_t)NUSER * 4);
  p.flag_l  = (int*)take((size_t)p.NLOC * 4);
  p.ticket  = (int*)take(256);
  size_t zbytes = off - z0;

  hipMemsetAsync(ws + z0, 0, zbytes, stream);
  hipLaunchKernelGGL(k_init, dim3(512), dim3(NT), 0, stream, p);
  hipLaunchKernelGGL(k_main, dim3(p.NWORK), dim3(NT), 0, stream, p);
  hipLaunchKernelGGL(k_fin,  dim3(1),   dim3(NT), 0, stream, p);
}

// Round 6
// 190.792 us; speedup vs baseline: 1.8333x; 1.7628x over previous
//
#include <hip/hip_runtime.h>

#define DEVINL static __device__ __forceinline__

typedef float f32x4 __attribute__((ext_vector_type(4)));

constexpr int NUSER = 100000;
constexpr int D     = 128;
constexpr int METAN = 640;
constexpr int NT    = 256;
constexpr int CH    = 4;      // events per worker block (chunk)
constexpr int KP4   = 160;    // W_pred K in float4 (640/4)
constexpr int KR4   = 96;     // RNN combined K in float4 (384/4), segment-aligned
constexpr int TROWS = 256;    // rows per copy ticket

struct Params {
  const float *emb_in, *stat, *kg;
  const float *Wihu, *bihu, *Whhu, *bhhu;
  const float *Wihl, *bihl, *Whhl, *bhhl;
  const float *wproj, *bproj, *lng, *lnb, *Wpred, *bpred;
  const float *deltau, *deltal;
  const int *idxu, *idxl, *idxp, *idxk;
  float *emb;        // d_out [N*D]
  float *loss_slot;  // d_out + N*D
  float *WpredT;     // ws [160][256] float4
  float *WrnnT;      // ws [96][256] float4 (k: [other(128)|kg(128)|own(128)])
  float *brnn;       // ws [256]  (bih+bhh)
  float *wcol;       // ws [256]  (Wih[:,256] = delta column)
  float *loss_ev;    // ws [E]
  int *cnt_u, *cnt_w, *cnt_t;
  int *flag_u, *flag_l;
  int *ticket;
  int E, N, NLOC, NWORK;
};

DEVINL float loadx(const float* p) {
  return __hip_atomic_load(p, __ATOMIC_RELAXED, __HIP_MEMORY_SCOPE_AGENT);
}
DEVINL void storex(float* p, float v) {
  __hip_atomic_store(p, v, __ATOMIC_RELAXED, __HIP_MEMORY_SCOPE_AGENT);
}
DEVINL float dot4(float4 a, float4 b) { return a.x*b.x + a.y*b.y + a.z*b.z + a.w*b.w; }

DEVINL float4 block_sum4(float4 v, float4* s4) {
  #pragma unroll
  for (int o = 32; o; o >>= 1) {
    v.x += __shfl_xor(v.x, o, 64); v.y += __shfl_xor(v.y, o, 64);
    v.z += __shfl_xor(v.z, o, 64); v.w += __shfl_xor(v.w, o, 64);
  }
  if ((threadIdx.x & 63) == 0) s4[threadIdx.x >> 6] = v;
  __syncthreads();
  float4 r;
  r.x = s4[0].x + s4[1].x + s4[2].x + s4[3].x;
  r.y = s4[0].y + s4[1].y + s4[2].y + s4[3].y;
  r.z = s4[0].z + s4[1].z + s4[2].z + s4[3].z;
  r.w = s4[0].w + s4[1].w + s4[2].w + s4[3].w;
  __syncthreads();
  return r;
}

// per-wave-pair sums: {sum over tid<128, sum over tid>=128}
DEVINL void half_sum4(float4 v, float4* s4, float4* lo, float4* hi) {
  #pragma unroll
  for (int o = 32; o; o >>= 1) {
    v.x += __shfl_xor(v.x, o, 64); v.y += __shfl_xor(v.y, o, 64);
    v.z += __shfl_xor(v.z, o, 64); v.w += __shfl_xor(v.w, o, 64);
  }
  if ((threadIdx.x & 63) == 0) s4[threadIdx.x >> 6] = v;
  __syncthreads();
  lo->x = s4[0].x + s4[1].x; lo->y = s4[0].y + s4[1].y;
  lo->z = s4[0].z + s4[1].z; lo->w = s4[0].w + s4[1].w;
  hi->x = s4[2].x + s4[3].x; hi->y = s4[2].y + s4[3].y;
  hi->z = s4[2].z + s4[3].z; hi->w = s4[2].w + s4[3].w;
  __syncthreads();
}

__global__ void k_init(Params p) {
  int tid = blockIdx.x * NT + threadIdx.x;
  int stride = gridDim.x * NT;
  for (int e = tid; e < p.E; e += stride) {
    p.flag_u[p.idxu[e]] = 1;
    p.flag_l[p.idxl[e]] = 1;
  }
  for (int idx = tid; idx < 256 * KP4; idx += stride) {
    int j = idx / KP4, k4 = idx - j * KP4;
    float4 v = *(const float4*)(p.Wpred + (size_t)j * METAN + k4 * 4);
    ((float4*)p.WpredT)[k4 * 256 + j] = v;
  }
  for (int idx = tid; idx < 256 * KR4; idx += stride) {
    int j = idx / KR4, k4 = idx - j * KR4;
    int i = j & 127;
    const float* Wih = (j < 128) ? p.Wihu : p.Wihl;
    const float* Whh = (j < 128) ? p.Whhu : p.Whhl;
    float4 v; float* vp = (float*)&v;
    #pragma unroll
    for (int e = 0; e < 4; ++e) {
      int k = k4 * 4 + e;
      vp[e] = (k < 256) ? Wih[(size_t)i * 257 + k] : Whh[(size_t)i * 128 + (k - 256)];
    }
    ((float4*)p.WrnnT)[k4 * 256 + j] = v;
  }
  for (int j = tid; j < 256; j += stride) {
    int i = j & 127;
    p.brnn[j] = (j < 128) ? p.bihu[i] + p.bhhu[i] : p.bihl[i] + p.bhhl[i];
    p.wcol[j] = (j < 128) ? p.Wihu[(size_t)i * 257 + 256] : p.Wihl[(size_t)i * 257 + 256];
  }
}

__global__ __launch_bounds__(NT, 2) void k_main(Params p) {
  __shared__ __align__(16) float s_meta[CH][METAN];
  __shared__ __align__(16) float s_u[CH][D], s_l[CH][D], s_p[CH][D], s_kg[CH][D], s_sil[CH][D];
  __shared__ float4 s_r4[4];
  __shared__ unsigned long long s_redu[4][CH];
  __shared__ int s_ev[8][CH];     // 0:iu 1:il 2:ip 3:A 4:WL 5:B 6:C 7:ik
  __shared__ float s_dd[2][CH];
  __shared__ int s_tile;

  const int tid = threadIdx.x, w = tid >> 6, lane = tid & 63;

  const int base = blockIdx.x * CH;
  const int nev  = min(CH, p.E - base);

  if (nev > 0) {
    int iu_[CH], il_[CH], ip_[CH], ik_[CH];
    float du_[CH], dl_[CH];
    #pragma unroll
    for (int e = 0; e < CH; ++e) {
      int t = base + e; bool v = e < nev;
      iu_[e] = v ? p.idxu[t] : -1;
      il_[e] = v ? p.idxl[t] : -1;
      ip_[e] = v ? p.idxp[t] : -1;
      ik_[e] = v ? p.idxk[t] : 0;
      du_[e] = v ? p.deltau[t] : 0.f;
      dl_[e] = v ? p.deltal[t] : 0.f;
    }

    // ---- dependency counts over events s < base ----
    unsigned long long pk[CH] = {0ull,0ull,0ull,0ull};
    for (int s = tid; s < base; s += NT) {
      int ius = p.idxu[s], ils = p.idxl[s], ips = p.idxp[s];
      #pragma unroll
      for (int e = 0; e < CH; ++e) {
        unsigned long long a  = (ius == iu_[e]);
        unsigned long long wl = (ils == il_[e]);
        unsigned long long b  = (unsigned long long)((ils == il_[e]) + (ips == il_[e]));
        unsigned long long c  = (ils == ip_[e]);
        pk[e] += a | (wl << 16) | (b << 32) | (c << 48);
      }
    }
    #pragma unroll
    for (int o = 32; o; o >>= 1) {
      #pragma unroll
      for (int e = 0; e < CH; ++e) pk[e] += __shfl_xor(pk[e], o, 64);
    }
    if (lane == 0) {
      #pragma unroll
      for (int e = 0; e < CH; ++e) s_redu[w][e] = pk[e];
    }
    __syncthreads();
    #pragma unroll
    for (int e = 0; e < CH; ++e)
      pk[e] = s_redu[0][e] + s_redu[1][e] + s_redu[2][e] + s_redu[3][e];
    __syncthreads();

    int A_[CH], WL_[CH], B_[CH], C_[CH];
    #pragma unroll
    for (int e = 0; e < CH; ++e) {
      int a  = (int)(pk[e] & 0xffff),        wl = (int)((pk[e] >> 16) & 0xffff);
      int b  = (int)((pk[e] >> 32) & 0xffff), c = (int)((pk[e] >> 48) & 0xffff);
      #pragma unroll
      for (int s2 = 0; s2 < CH; ++s2) if (s2 < e) {
        a  += (iu_[s2] == iu_[e]);
        wl += (il_[s2] == il_[e]);
        b  += (il_[s2] == il_[e]) + (ip_[s2] == il_[e]);
        c  += (il_[s2] == ip_[e]);
      }
      A_[e] = a; WL_[e] = wl; B_[e] = b; C_[e] = c;
    }
    bool internal = false;
    #pragma unroll
    for (int t2 = 1; t2 < CH; ++t2) if (t2 < nev) {
      #pragma unroll
      for (int s2 = 0; s2 < t2; ++s2)
        internal |= (iu_[s2] == iu_[t2]) | (il_[s2] == il_[t2]) |
                    (il_[s2] == ip_[t2]) | (ip_[s2] == il_[t2]);
    }

    if (tid == 0) {
      #pragma unroll
      for (int e = 0; e < CH; ++e) {
        s_ev[0][e] = iu_[e]; s_ev[1][e] = il_[e]; s_ev[2][e] = ip_[e];
        s_ev[3][e] = A_[e];  s_ev[4][e] = WL_[e]; s_ev[5][e] = B_[e];
        s_ev[6][e] = C_[e];  s_ev[7][e] = ik_[e];
        s_dd[0][e] = du_[e]; s_dd[1][e] = dl_[e];
      }
    }
    __syncthreads();

    auto SPIN = [&](int b0, int b1) {
      if (w == 0) {
        int e = b0 + lane;
        bool act = lane < (b1 - b0);
        int iu = 0, il = 0, ip = 0, A = 0, Bc = 0, Cc = 0;
        if (act) {
          iu = s_ev[0][e]; il = s_ev[1][e]; ip = s_ev[2][e];
          A = s_ev[3][e]; Bc = s_ev[5][e]; Cc = s_ev[6][e];
        }
        int guard = 0;
        while (true) {
          bool ok = !act ||
            (__hip_atomic_load(&p.cnt_u[iu], __ATOMIC_RELAXED, __HIP_MEMORY_SCOPE_AGENT) >= A &&
             __hip_atomic_load(&p.cnt_t[il], __ATOMIC_RELAXED, __HIP_MEMORY_SCOPE_AGENT) >= Bc &&
             __hip_atomic_load(&p.cnt_w[ip], __ATOMIC_RELAXED, __HIP_MEMORY_SCOPE_AGENT) >= Cc);
          if (__all(ok)) break;
          if (++guard > (1 << 22)) break;   // safety valve
          __builtin_amdgcn_s_sleep(1);
        }
      }
      __syncthreads();
    };

    auto PROCESS = [&](int b0, int b1) {
      // ---- phase 1: row loads (wave w handles event w) ----
      {
        int e = w;
        if (e >= b0 && e < b1) {
          int iu = s_ev[0][e], ilr = s_ev[1][e] + NUSER, ipr = s_ev[2][e] + NUSER;
          int A = s_ev[3][e], WL = s_ev[4][e], Ck = s_ev[6][e], ik = s_ev[7][e];
          int i0 = lane * 2;
          #pragma unroll
          for (int j = 0; j < 2; ++j) {
            int i = i0 + j;
            s_u[e][i] = A  ? loadx(p.emb + (size_t)iu  * D + i) : p.emb_in[(size_t)iu  * D + i];
            s_l[e][i] = WL ? loadx(p.emb + (size_t)ilr * D + i) : p.emb_in[(size_t)ilr * D + i];
            s_p[e][i] = Ck ? loadx(p.emb + (size_t)ipr * D + i) : p.emb_in[(size_t)ipr * D + i];
          }
          int h2 = lane >> 5, li = (lane & 31) * 4;
          if (h2 == 0) {
            *(float4*)&s_kg[e][li]         = *(const float4*)(p.kg   + (size_t)ik  * D + li);
            *(float4*)&s_meta[e][512 + li] = *(const float4*)(p.stat + (size_t)iu  * D + li);
          } else {
            *(float4*)&s_meta[e][384 + li] = *(const float4*)(p.stat + (size_t)ipr * D + li);
            *(float4*)&s_sil[e][li]        = *(const float4*)(p.stat + (size_t)ilr * D + li);
          }
        }
      }
      __syncthreads();

      // ---- phase 2 (CRITICAL PATH): RNN matvec -> normalize -> store -> signal ----
      const bool uc = (tid < 128);
      const float4* xo0 = (const float4*)(uc ? s_l[0] : s_u[0]);
      const float4* xo1 = (const float4*)(uc ? s_l[1] : s_u[1]);
      const float4* xo2 = (const float4*)(uc ? s_l[2] : s_u[2]);
      const float4* xo3 = (const float4*)(uc ? s_l[3] : s_u[3]);
      const float4* xk0 = (const float4*)s_kg[0];
      const float4* xk1 = (const float4*)s_kg[1];
      const float4* xk2 = (const float4*)s_kg[2];
      const float4* xk3 = (const float4*)s_kg[3];
      const float4* xs0 = (const float4*)(uc ? s_u[0] : s_l[0]);
      const float4* xs1 = (const float4*)(uc ? s_u[1] : s_l[1]);
      const float4* xs2 = (const float4*)(uc ? s_u[2] : s_l[2]);
      const float4* xs3 = (const float4*)(uc ? s_u[3] : s_l[3]);
      float ra0 = 0.f, ra1 = 0.f, ra2 = 0.f, ra3 = 0.f;
      const float4* wr = (const float4*)p.WrnnT + tid;
      #pragma unroll 8
      for (int k4 = 0; k4 < 32; ++k4) {
        float4 wv = wr[k4 * 256];
        ra0 += dot4(wv, xo0[k4]); ra1 += dot4(wv, xo1[k4]);
        ra2 += dot4(wv, xo2[k4]); ra3 += dot4(wv, xo3[k4]);
      }
      #pragma unroll 8
      for (int k4 = 32; k4 < 64; ++k4) {
        float4 wv = wr[k4 * 256];
        ra0 += dot4(wv, xk0[k4-32]); ra1 += dot4(wv, xk1[k4-32]);
        ra2 += dot4(wv, xk2[k4-32]); ra3 += dot4(wv, xk3[k4-32]);
      }
      #pragma unroll 8
      for (int k4 = 64; k4 < 96; ++k4) {
        float4 wv = wr[k4 * 256];
        ra0 += dot4(wv, xs0[k4-64]); ra1 += dot4(wv, xs1[k4-64]);
        ra2 += dot4(wv, xs2[k4-64]); ra3 += dot4(wv, xs3[k4-64]);
      }
      float brn = p.brnn[tid], wcv = p.wcol[tid];
      float d0 = uc ? s_dd[0][0] : s_dd[1][0];
      float d1 = uc ? s_dd[0][1] : s_dd[1][1];
      float d2 = uc ? s_dd[0][2] : s_dd[1][2];
      float d3 = uc ? s_dd[0][3] : s_dd[1][3];
      float h0 = tanhf(ra0 + brn + wcv * d0), h1 = tanhf(ra1 + brn + wcv * d1);
      float h2v = tanhf(ra2 + brn + wcv * d2), h3 = tanhf(ra3 + brn + wcv * d3);

      float4 SU, SL;
      half_sum4(make_float4(h0*h0, h1*h1, h2v*h2v, h3*h3), s_r4, &SU, &SL);
      float s0 = uc ? SU.x : SL.x, s1 = uc ? SU.y : SL.y;
      float s2 = uc ? SU.z : SL.z, s3 = uc ? SU.w : SL.w;
      float n0 = h0 / fmaxf(sqrtf(s0), 1e-12f), n1 = h1 / fmaxf(sqrtf(s1), 1e-12f);
      float n2 = h2v / fmaxf(sqrtf(s2), 1e-12f), n3 = h3 / fmaxf(sqrtf(s3), 1e-12f);

      float nv[CH] = {n0, n1, n2, n3};
      #pragma unroll
      for (int e = 0; e < CH; ++e) if (e >= b0 && e < b1) {
        if (tid < 128) storex(p.emb + (size_t)s_ev[0][e] * D + tid, nv[e]);
        else           storex(p.emb + ((size_t)s_ev[1][e] + NUSER) * D + (tid - 128), nv[e]);
      }
      __syncthreads();   // drain stores block-wide

      if (tid >= b0 && tid < b1) {
        __threadfence();                       // release
        atomicAdd(&p.cnt_u[s_ev[0][tid]], 1);  // SIGNAL — successors released here
        atomicAdd(&p.cnt_t[s_ev[1][tid]], 1);
        atomicAdd(&p.cnt_w[s_ev[1][tid]], 1);
        atomicAdd(&p.cnt_t[s_ev[2][tid]], 1);
      }

      // ---- phase 3 (off-chain): LN + proj + pred + losses ----
      {
        int e = w;
        if (e >= b0 && e < b1) {
          float du = s_dd[0][e];
          float4 xv = (lane < 32) ? *(const float4*)&s_p[e][lane * 4]
                                  : *(const float4*)&s_kg[e][(lane - 32) * 4];
          float sm = xv.x + xv.y + xv.z + xv.w;
          #pragma unroll
          for (int o = 32; o; o >>= 1) sm += __shfl_xor(sm, o, 64);
          float mu = sm * (1.f / 256.f);
          float4 d = make_float4(xv.x - mu, xv.y - mu, xv.z - mu, xv.w - mu);
          float vs = d.x*d.x + d.y*d.y + d.z*d.z + d.w*d.w;
          #pragma unroll
          for (int o = 32; o; o >>= 1) vs += __shfl_xor(vs, o, 64);
          float rstd = rsqrtf(vs * (1.f / 256.f) + 1e-5f);
          int idx = lane * 4;
          float4 g  = *(const float4*)&p.lng[idx];
          float4 bb = *(const float4*)&p.lnb[idx];
          *(float4*)&s_meta[e][128 + idx] = make_float4(
            d.x*rstd*g.x + bb.x, d.y*rstd*g.y + bb.y,
            d.z*rstd*g.z + bb.z, d.w*rstd*g.w + bb.w);

          int i0 = lane * 2;
          #pragma unroll
          for (int j = 0; j < 2; ++j) {
            int i = i0 + j;
            s_meta[e][i] = s_u[e][i] * (1.f + p.wproj[i] * du + p.bproj[i]);
          }
        }
      }
      __syncthreads();

      const float4* m40 = (const float4*)&s_meta[0][0];
      const float4* m41 = (const float4*)&s_meta[1][0];
      const float4* m42 = (const float4*)&s_meta[2][0];
      const float4* m43 = (const float4*)&s_meta[3][0];
      float pa0 = 0.f, pa1 = 0.f, pa2 = 0.f, pa3 = 0.f;
      const float4* wp = (const float4*)p.WpredT + tid;
      #pragma unroll 8
      for (int k4 = 0; k4 < KP4; ++k4) {
        float4 wv = wp[k4 * 256];
        pa0 += dot4(wv, m40[k4]); pa1 += dot4(wv, m41[k4]);
        pa2 += dot4(wv, m42[k4]); pa3 += dot4(wv, m43[k4]);
      }
      float bp = p.bpred[tid];
      float4 ep2;
      {
        float tg0 = uc ? s_l[0][tid] : s_sil[0][tid - 128];
        float tg1 = uc ? s_l[1][tid] : s_sil[1][tid - 128];
        float tg2 = uc ? s_l[2][tid] : s_sil[2][tid - 128];
        float tg3 = uc ? s_l[3][tid] : s_sil[3][tid - 128];
        float e0 = pa0 + bp - tg0, e1 = pa1 + bp - tg1;
        float e2 = pa2 + bp - tg2, e3 = pa3 + bp - tg3;
        ep2 = make_float4(e0*e0, e1*e1, e2*e2, e3*e3);
      }
      float4 LP = block_sum4(ep2, s_r4);

      float o0 = uc ? s_u[0][tid] : s_l[0][tid - 128];
      float o1 = uc ? s_u[1][tid] : s_l[1][tid - 128];
      float o2 = uc ? s_u[2][tid] : s_l[2][tid - 128];
      float o3 = uc ? s_u[3][tid] : s_l[3][tid - 128];
      float q0 = n0 - o0, q1 = n1 - o1, q2 = n2 - o2, q3 = n3 - o3;
      float4 LE = block_sum4(make_float4(q0*q0, q1*q1, q2*q2, q3*q3), s_r4);

      if (tid >= b0 && tid < b1) {
        float lp = (tid == 0) ? LP.x : (tid == 1) ? LP.y : (tid == 2) ? LP.z : LP.w;
        float le = (tid == 0) ? LE.x : (tid == 1) ? LE.y : (tid == 2) ? LE.z : LE.w;
        p.loss_ev[base + tid] = lp * (1.f / 256.f) + le * (1.f / 128.f);
      }
    };

    if (!internal) {
      SPIN(0, nev);
      PROCESS(0, nev);
    } else {
      for (int e = 0; e < nev; ++e) {
        SPIN(e, e + 1);
        PROCESS(e, e + 1);
      }
    }
  }

  // ---- copy phase: ticket-based, nontemporal (keep weights L2-resident) ----
  const int ntiles = (p.N + TROWS - 1) / TROWS;
  const f32x4* src = (const f32x4*)p.emb_in;
  f32x4* dst = (f32x4*)p.emb;
  for (;;) {
    if (tid == 0) s_tile = atomicAdd(p.ticket, 1);
    __syncthreads();
    int tile = s_tile;
    __syncthreads();
    if (tile >= ntiles) break;
    int r0 = tile * TROWS;
    int nrow = min(TROWS, p.N - r0);
    if (nrow == TROWS) {
      #pragma unroll 4
      for (int k = 0; k < TROWS * 32 / NT; ++k) {
        int idx = tid + k * NT;
        int row = r0 + (idx >> 5);
        int fl = (row < NUSER) ? p.flag_u[row] : p.flag_l[row - NUSER];
        if (!fl) {
          size_t g = (size_t)row * 32 + (idx & 31);
          __builtin_nontemporal_store(__builtin_nontemporal_load(src + g), dst + g);
        }
      }
    } else {
      for (int idx = tid; idx < nrow * 32; idx += NT) {
        int row = r0 + (idx >> 5);
        int fl = (row < NUSER) ? p.flag_u[row] : p.flag_l[row - NUSER];
        if (!fl) {
          size_t g = (size_t)row * 32 + (idx & 31);
          __builtin_nontemporal_store(__builtin_nontemporal_load(src + g), dst + g);
        }
      }
    }
  }
}

__global__ void k_fin(Params p) {
  __shared__ float4 s_r4[4];
  float v = 0.f;
  for (int i = threadIdx.x; i < p.E; i += NT) v += p.loss_ev[i];
  float4 r = block_sum4(make_float4(v, 0.f, 0.f, 0.f), s_r4);
  if (threadIdx.x == 0) p.loss_slot[0] = r.x;
}

extern "C" void kernel_launch(void* const* d_in, const int* in_sizes, int n_in,
                              void* d_out, int out_size, void* d_ws, size_t ws_size,
                              hipStream_t stream) {
  Params p;
  p.emb_in = (const float*)d_in[0];
  p.stat   = (const float*)d_in[1];
  p.kg     = (const float*)d_in[2];
  p.Wihu = (const float*)d_in[3];   p.bihu = (const float*)d_in[4];
  p.Whhu = (const float*)d_in[5];   p.bhhu = (const float*)d_in[6];
  p.Wihl = (const float*)d_in[7];   p.bihl = (const float*)d_in[8];
  p.Whhl = (const float*)d_in[9];   p.bhhl = (const float*)d_in[10];
  p.wproj = (const float*)d_in[11]; p.bproj = (const float*)d_in[12];
  p.lng  = (const float*)d_in[13];  p.lnb  = (const float*)d_in[14];
  p.Wpred = (const float*)d_in[15]; p.bpred = (const float*)d_in[16];
  p.deltau = (const float*)d_in[17];
  p.deltal = (const float*)d_in[18];
  p.idxu = (const int*)d_in[19];
  p.idxl = (const int*)d_in[20];
  p.idxp = (const int*)d_in[21];
  p.idxk = (const int*)d_in[22];

  p.E    = in_sizes[17];
  p.N    = in_sizes[0] / D;
  p.NLOC = p.N - NUSER;
  p.NWORK = (p.E + CH - 1) / CH;

  p.emb       = (float*)d_out;
  p.loss_slot = (float*)d_out + (size_t)p.N * D;

  char* ws = (char*)d_ws;
  size_t off = 0;
  auto take = [&](size_t bytes) {
    void* r = ws + off;
    off += (bytes + 255) & ~(size_t)255;
    return r;
  };
  p.WpredT  = (float*)take((size_t)KP4 * 256 * 16);
  p.WrnnT   = (float*)take((size_t)KR4 * 256 * 16);
  p.brnn    = (float*)take(256 * 4);
  p.wcol    = (float*)take(256 * 4);
  p.loss_ev = (float*)take((size_t)p.E * 4);
  size_t z0 = off;
  p.cnt_u   = (int*)take((size_t)NUSER * 4);
  p.cnt_w   = (int*)take((size_t)p.NLOC * 4);
  p.cnt_t   = (int*)take((size_t)p.NLOC * 4);
  p.flag_u  = (int*)take((size_t)NUSER * 4);
  p.flag_l  = (int*)take((size_t)p.NLOC * 4);
  p.ticket  = (int*)take(256);
  size_t zbytes = off - z0;

  hipMemsetAsync(ws + z0, 0, zbytes, stream);
  hipLaunchKernelGGL(k_init, dim3(512), dim3(NT), 0, stream, p);
  hipLaunchKernelGGL(k_main, dim3(p.NWORK), dim3(NT), 0, stream, p);
  hipLaunchKernelGGL(k_fin,  dim3(1),   dim3(NT), 0, stream, p);
}

// Round 7
// 188.030 us; speedup vs baseline: 1.8603x; 1.0147x over previous
//
#include <hip/hip_runtime.h>

#define DEVINL static __device__ __forceinline__

typedef float f32x4 __attribute__((ext_vector_type(4)));

constexpr int NUSER = 100000;
constexpr int D     = 128;
constexpr int METAN = 640;
constexpr int NT    = 256;
constexpr int CH    = 4;      // events per worker block (chunk)
constexpr int KP4   = 160;    // W_pred K in float4 (640/4)
constexpr int KR4   = 96;     // RNN combined K in float4 (384/4), segment-aligned
constexpr int TROWS = 256;    // rows per copy ticket

struct Params {
  const float *emb_in, *stat, *kg;
  const float *Wihu, *bihu, *Whhu, *bhhu;
  const float *Wihl, *bihl, *Whhl, *bhhl;
  const float *wproj, *bproj, *lng, *lnb, *Wpred, *bpred;
  const float *deltau, *deltal;
  const int *idxu, *idxl, *idxp, *idxk;
  float *emb;        // d_out [N*D]
  float *loss_slot;  // d_out + N*D
  float *WpredT;     // ws [160][256] float4
  float *WrnnT;      // ws [96][256] float4 (k: [other(128)|kg(128)|own(128)])
  float *brnn;       // ws [256]  (bih+bhh)
  float *wcol;       // ws [256]  (Wih[:,256] = delta column)
  float *loss_ev;    // ws [E]
  int *cnt_u, *cnt_w, *cnt_t;
  int *flag_u, *flag_l;
  int *ticket;
  int E, N, NLOC, NWORK;
};

DEVINL float loadx(const float* p) {
  return __hip_atomic_load(p, __ATOMIC_RELAXED, __HIP_MEMORY_SCOPE_AGENT);
}
DEVINL void storex(float* p, float v) {
  __hip_atomic_store(p, v, __ATOMIC_RELAXED, __HIP_MEMORY_SCOPE_AGENT);
}
DEVINL void sigadd(int* pp) {  // fire-and-forget agent-scope increment (no cache inv)
  __hip_atomic_fetch_add(pp, 1, __ATOMIC_RELAXED, __HIP_MEMORY_SCOPE_AGENT);
}
DEVINL float dot4(float4 a, float4 b) { return a.x*b.x + a.y*b.y + a.z*b.z + a.w*b.w; }

DEVINL float4 block_sum4(float4 v, float4* s4) {
  #pragma unroll
  for (int o = 32; o; o >>= 1) {
    v.x += __shfl_xor(v.x, o, 64); v.y += __shfl_xor(v.y, o, 64);
    v.z += __shfl_xor(v.z, o, 64); v.w += __shfl_xor(v.w, o, 64);
  }
  if ((threadIdx.x & 63) == 0) s4[threadIdx.x >> 6] = v;
  __syncthreads();
  float4 r;
  r.x = s4[0].x + s4[1].x + s4[2].x + s4[3].x;
  r.y = s4[0].y + s4[1].y + s4[2].y + s4[3].y;
  r.z = s4[0].z + s4[1].z + s4[2].z + s4[3].z;
  r.w = s4[0].w + s4[1].w + s4[2].w + s4[3].w;
  __syncthreads();
  return r;
}

// per-wave-pair sums: {sum over tid<128, sum over tid>=128}
DEVINL void half_sum4(float4 v, float4* s4, float4* lo, float4* hi) {
  #pragma unroll
  for (int o = 32; o; o >>= 1) {
    v.x += __shfl_xor(v.x, o, 64); v.y += __shfl_xor(v.y, o, 64);
    v.z += __shfl_xor(v.z, o, 64); v.w += __shfl_xor(v.w, o, 64);
  }
  if ((threadIdx.x & 63) == 0) s4[threadIdx.x >> 6] = v;
  __syncthreads();
  lo->x = s4[0].x + s4[1].x; lo->y = s4[0].y + s4[1].y;
  lo->z = s4[0].z + s4[1].z; lo->w = s4[0].w + s4[1].w;
  hi->x = s4[2].x + s4[3].x; hi->y = s4[2].y + s4[3].y;
  hi->z = s4[2].z + s4[3].z; hi->w = s4[2].w + s4[3].w;
  __syncthreads();
}

__global__ void k_init(Params p) {
  int tid = blockIdx.x * NT + threadIdx.x;
  int stride = gridDim.x * NT;
  for (int e = tid; e < p.E; e += stride) {
    p.flag_u[p.idxu[e]] = 1;
    p.flag_l[p.idxl[e]] = 1;
  }
  for (int idx = tid; idx < 256 * KP4; idx += stride) {
    int j = idx / KP4, k4 = idx - j * KP4;
    float4 v = *(const float4*)(p.Wpred + (size_t)j * METAN + k4 * 4);
    ((float4*)p.WpredT)[k4 * 256 + j] = v;
  }
  for (int idx = tid; idx < 256 * KR4; idx += stride) {
    int j = idx / KR4, k4 = idx - j * KR4;
    int i = j & 127;
    const float* Wih = (j < 128) ? p.Wihu : p.Wihl;
    const float* Whh = (j < 128) ? p.Whhu : p.Whhl;
    float4 v; float* vp = (float*)&v;
    #pragma unroll
    for (int e = 0; e < 4; ++e) {
      int k = k4 * 4 + e;
      vp[e] = (k < 256) ? Wih[(size_t)i * 257 + k] : Whh[(size_t)i * 128 + (k - 256)];
    }
    ((float4*)p.WrnnT)[k4 * 256 + j] = v;
  }
  for (int j = tid; j < 256; j += stride) {
    int i = j & 127;
    p.brnn[j] = (j < 128) ? p.bihu[i] + p.bhhu[i] : p.bihl[i] + p.bhhl[i];
    p.wcol[j] = (j < 128) ? p.Wihu[(size_t)i * 257 + 256] : p.Wihl[(size_t)i * 257 + 256];
  }
}

__global__ __launch_bounds__(NT, 2) void k_main(Params p) {
  __shared__ __align__(16) float s_meta[CH][METAN];
  __shared__ __align__(16) float s_u[CH][D], s_l[CH][D], s_p[CH][D], s_kg[CH][D], s_sil[CH][D];
  __shared__ float4 s_r4[4];
  __shared__ unsigned long long s_redu[4][CH];
  __shared__ int s_ev[8][CH];     // 0:iu 1:il 2:ip 3:A 4:WL 5:B 6:C 7:ik
  __shared__ float s_dd[2][CH];
  __shared__ int s_tile;

  const int tid = threadIdx.x, w = tid >> 6, lane = tid & 63;

  const int base = blockIdx.x * CH;
  const int nev  = min(CH, p.E - base);

  if (nev > 0) {
    int iu_[CH], il_[CH], ip_[CH], ik_[CH];
    float du_[CH], dl_[CH];
    #pragma unroll
    for (int e = 0; e < CH; ++e) {
      int t = base + e; bool v = e < nev;
      iu_[e] = v ? p.idxu[t] : -1;
      il_[e] = v ? p.idxl[t] : -1;
      ip_[e] = v ? p.idxp[t] : -1;
      ik_[e] = v ? p.idxk[t] : 0;
      du_[e] = v ? p.deltau[t] : 0.f;
      dl_[e] = v ? p.deltal[t] : 0.f;
    }

    // ---- dependency counts over events s < base ----
    unsigned long long pk[CH] = {0ull,0ull,0ull,0ull};
    for (int s = tid; s < base; s += NT) {
      int ius = p.idxu[s], ils = p.idxl[s], ips = p.idxp[s];
      #pragma unroll
      for (int e = 0; e < CH; ++e) {
        unsigned long long a  = (ius == iu_[e]);
        unsigned long long wl = (ils == il_[e]);
        unsigned long long b  = (unsigned long long)((ils == il_[e]) + (ips == il_[e]));
        unsigned long long c  = (ils == ip_[e]);
        pk[e] += a | (wl << 16) | (b << 32) | (c << 48);
      }
    }
    #pragma unroll
    for (int o = 32; o; o >>= 1) {
      #pragma unroll
      for (int e = 0; e < CH; ++e) pk[e] += __shfl_xor(pk[e], o, 64);
    }
    if (lane == 0) {
      #pragma unroll
      for (int e = 0; e < CH; ++e) s_redu[w][e] = pk[e];
    }
    __syncthreads();
    #pragma unroll
    for (int e = 0; e < CH; ++e)
      pk[e] = s_redu[0][e] + s_redu[1][e] + s_redu[2][e] + s_redu[3][e];
    __syncthreads();

    int A_[CH], WL_[CH], B_[CH], C_[CH];
    #pragma unroll
    for (int e = 0; e < CH; ++e) {
      int a  = (int)(pk[e] & 0xffff),        wl = (int)((pk[e] >> 16) & 0xffff);
      int b  = (int)((pk[e] >> 32) & 0xffff), c = (int)((pk[e] >> 48) & 0xffff);
      #pragma unroll
      for (int s2 = 0; s2 < CH; ++s2) if (s2 < e) {
        a  += (iu_[s2] == iu_[e]);
        wl += (il_[s2] == il_[e]);
        b  += (il_[s2] == il_[e]) + (ip_[s2] == il_[e]);
        c  += (il_[s2] == ip_[e]);
      }
      A_[e] = a; WL_[e] = wl; B_[e] = b; C_[e] = c;
    }
    bool internal = false;
    #pragma unroll
    for (int t2 = 1; t2 < CH; ++t2) if (t2 < nev) {
      #pragma unroll
      for (int s2 = 0; s2 < t2; ++s2)
        internal |= (iu_[s2] == iu_[t2]) | (il_[s2] == il_[t2]) |
                    (il_[s2] == ip_[t2]) | (ip_[s2] == il_[t2]);
    }

    if (tid == 0) {
      #pragma unroll
      for (int e = 0; e < CH; ++e) {
        s_ev[0][e] = iu_[e]; s_ev[1][e] = il_[e]; s_ev[2][e] = ip_[e];
        s_ev[3][e] = A_[e];  s_ev[4][e] = WL_[e]; s_ev[5][e] = B_[e];
        s_ev[6][e] = C_[e];  s_ev[7][e] = ik_[e];
        s_dd[0][e] = du_[e]; s_dd[1][e] = dl_[e];
      }
    }
    __syncthreads();

    auto SPIN = [&](int b0, int b1) {
      if (w == 0) {
        int e = b0 + lane;
        bool act = lane < (b1 - b0);
        int iu = 0, il = 0, ip = 0, A = 0, Bc = 0, Cc = 0;
        if (act) {
          iu = s_ev[0][e]; il = s_ev[1][e]; ip = s_ev[2][e];
          A = s_ev[3][e]; Bc = s_ev[5][e]; Cc = s_ev[6][e];
        }
        int guard = 0;
        while (true) {
          bool ok = !act ||
            (__hip_atomic_load(&p.cnt_u[iu], __ATOMIC_RELAXED, __HIP_MEMORY_SCOPE_AGENT) >= A &&
             __hip_atomic_load(&p.cnt_t[il], __ATOMIC_RELAXED, __HIP_MEMORY_SCOPE_AGENT) >= Bc &&
             __hip_atomic_load(&p.cnt_w[ip], __ATOMIC_RELAXED, __HIP_MEMORY_SCOPE_AGENT) >= Cc);
          if (__all(ok)) break;
          if (++guard > (1 << 22)) break;   // safety valve
          __builtin_amdgcn_s_sleep(1);
        }
      }
      __syncthreads();
    };

    auto PROCESS = [&](int b0, int b1) {
      // ---- phase 1: row loads (wave w handles event w) ----
      {
        int e = w;
        if (e >= b0 && e < b1) {
          int iu = s_ev[0][e], ilr = s_ev[1][e] + NUSER, ipr = s_ev[2][e] + NUSER;
          int A = s_ev[3][e], WL = s_ev[4][e], Ck = s_ev[6][e], ik = s_ev[7][e];
          int i0 = lane * 2;
          #pragma unroll
          for (int j = 0; j < 2; ++j) {
            int i = i0 + j;
            s_u[e][i] = A  ? loadx(p.emb + (size_t)iu  * D + i) : p.emb_in[(size_t)iu  * D + i];
            s_l[e][i] = WL ? loadx(p.emb + (size_t)ilr * D + i) : p.emb_in[(size_t)ilr * D + i];
            s_p[e][i] = Ck ? loadx(p.emb + (size_t)ipr * D + i) : p.emb_in[(size_t)ipr * D + i];
          }
          int h2 = lane >> 5, li = (lane & 31) * 4;
          if (h2 == 0) {
            *(float4*)&s_kg[e][li]         = *(const float4*)(p.kg   + (size_t)ik  * D + li);
            *(float4*)&s_meta[e][512 + li] = *(const float4*)(p.stat + (size_t)iu  * D + li);
          } else {
            *(float4*)&s_meta[e][384 + li] = *(const float4*)(p.stat + (size_t)ipr * D + li);
            *(float4*)&s_sil[e][li]        = *(const float4*)(p.stat + (size_t)ilr * D + li);
          }
        }
      }
      __syncthreads();

      // ---- phase 2 (CRITICAL PATH): RNN matvec -> normalize -> store -> signal ----
      const bool uc = (tid < 128);
      const float4* xo0 = (const float4*)(uc ? s_l[0] : s_u[0]);
      const float4* xo1 = (const float4*)(uc ? s_l[1] : s_u[1]);
      const float4* xo2 = (const float4*)(uc ? s_l[2] : s_u[2]);
      const float4* xo3 = (const float4*)(uc ? s_l[3] : s_u[3]);
      const float4* xk0 = (const float4*)s_kg[0];
      const float4* xk1 = (const float4*)s_kg[1];
      const float4* xk2 = (const float4*)s_kg[2];
      const float4* xk3 = (const float4*)s_kg[3];
      const float4* xs0 = (const float4*)(uc ? s_u[0] : s_l[0]);
      const float4* xs1 = (const float4*)(uc ? s_u[1] : s_l[1]);
      const float4* xs2 = (const float4*)(uc ? s_u[2] : s_l[2]);
      const float4* xs3 = (const float4*)(uc ? s_u[3] : s_l[3]);
      float ra0 = 0.f, ra1 = 0.f, ra2 = 0.f, ra3 = 0.f;
      const float4* wr = (const float4*)p.WrnnT + tid;
      #pragma unroll 8
      for (int k4 = 0; k4 < 32; ++k4) {
        float4 wv = wr[k4 * 256];
        ra0 += dot4(wv, xo0[k4]); ra1 += dot4(wv, xo1[k4]);
        ra2 += dot4(wv, xo2[k4]); ra3 += dot4(wv, xo3[k4]);
      }
      #pragma unroll 8
      for (int k4 = 32; k4 < 64; ++k4) {
        float4 wv = wr[k4 * 256];
        ra0 += dot4(wv, xk0[k4-32]); ra1 += dot4(wv, xk1[k4-32]);
        ra2 += dot4(wv, xk2[k4-32]); ra3 += dot4(wv, xk3[k4-32]);
      }
      #pragma unroll 8
      for (int k4 = 64; k4 < 96; ++k4) {
        float4 wv = wr[k4 * 256];
        ra0 += dot4(wv, xs0[k4-64]); ra1 += dot4(wv, xs1[k4-64]);
        ra2 += dot4(wv, xs2[k4-64]); ra3 += dot4(wv, xs3[k4-64]);
      }
      float brn = p.brnn[tid], wcv = p.wcol[tid];
      float d0 = uc ? s_dd[0][0] : s_dd[1][0];
      float d1 = uc ? s_dd[0][1] : s_dd[1][1];
      float d2 = uc ? s_dd[0][2] : s_dd[1][2];
      float d3 = uc ? s_dd[0][3] : s_dd[1][3];
      float h0 = tanhf(ra0 + brn + wcv * d0), h1 = tanhf(ra1 + brn + wcv * d1);
      float h2v = tanhf(ra2 + brn + wcv * d2), h3 = tanhf(ra3 + brn + wcv * d3);

      float4 SU, SL;
      half_sum4(make_float4(h0*h0, h1*h1, h2v*h2v, h3*h3), s_r4, &SU, &SL);
      float s0 = uc ? SU.x : SL.x, s1 = uc ? SU.y : SL.y;
      float s2 = uc ? SU.z : SL.z, s3 = uc ? SU.w : SL.w;
      float n0 = h0 / fmaxf(sqrtf(s0), 1e-12f), n1 = h1 / fmaxf(sqrtf(s1), 1e-12f);
      float n2 = h2v / fmaxf(sqrtf(s2), 1e-12f), n3 = h3 / fmaxf(sqrtf(s3), 1e-12f);

      float nv[CH] = {n0, n1, n2, n3};
      #pragma unroll
      for (int e = 0; e < CH; ++e) if (e >= b0 && e < b1) {
        if (tid < 128) storex(p.emb + (size_t)s_ev[0][e] * D + tid, nv[e]);
        else           storex(p.emb + ((size_t)s_ev[1][e] + NUSER) * D + (tid - 128), nv[e]);
      }
      __syncthreads();   // drains vmcnt(0): all sc1 stores visible at coherence point

      if (tid >= b0 && tid < b1) {
        // release fence (waitcnt only, NO L2 invalidate) + relaxed signal adds
        __builtin_amdgcn_fence(__ATOMIC_RELEASE, "agent");
        sigadd(&p.cnt_u[s_ev[0][tid]]);   // SIGNAL — successors released here
        sigadd(&p.cnt_t[s_ev[1][tid]]);
        sigadd(&p.cnt_w[s_ev[1][tid]]);
        sigadd(&p.cnt_t[s_ev[2][tid]]);
      }

      // ---- phase 3 (off-chain): LN + proj + pred + losses ----
      {
        int e = w;
        if (e >= b0 && e < b1) {
          float du = s_dd[0][e];
          float4 xv = (lane < 32) ? *(const float4*)&s_p[e][lane * 4]
                                  : *(const float4*)&s_kg[e][(lane - 32) * 4];
          float sm = xv.x + xv.y + xv.z + xv.w;
          #pragma unroll
          for (int o = 32; o; o >>= 1) sm += __shfl_xor(sm, o, 64);
          float mu = sm * (1.f / 256.f);
          float4 d = make_float4(xv.x - mu, xv.y - mu, xv.z - mu, xv.w - mu);
          float vs = d.x*d.x + d.y*d.y + d.z*d.z + d.w*d.w;
          #pragma unroll
          for (int o = 32; o; o >>= 1) vs += __shfl_xor(vs, o, 64);
          float rstd = rsqrtf(vs * (1.f / 256.f) + 1e-5f);
          int idx = lane * 4;
          float4 g  = *(const float4*)&p.lng[idx];
          float4 bb = *(const float4*)&p.lnb[idx];
          *(float4*)&s_meta[e][128 + idx] = make_float4(
            d.x*rstd*g.x + bb.x, d.y*rstd*g.y + bb.y,
            d.z*rstd*g.z + bb.z, d.w*rstd*g.w + bb.w);

          int i0 = lane * 2;
          #pragma unroll
          for (int j = 0; j < 2; ++j) {
            int i = i0 + j;
            s_meta[e][i] = s_u[e][i] * (1.f + p.wproj[i] * du + p.bproj[i]);
          }
        }
      }
      __syncthreads();

      const float4* m40 = (const float4*)&s_meta[0][0];
      const float4* m41 = (const float4*)&s_meta[1][0];
      const float4* m42 = (const float4*)&s_meta[2][0];
      const float4* m43 = (const float4*)&s_meta[3][0];
      float pa0 = 0.f, pa1 = 0.f, pa2 = 0.f, pa3 = 0.f;
      const float4* wp = (const float4*)p.WpredT + tid;
      #pragma unroll 8
      for (int k4 = 0; k4 < KP4; ++k4) {
        float4 wv = wp[k4 * 256];
        pa0 += dot4(wv, m40[k4]); pa1 += dot4(wv, m41[k4]);
        pa2 += dot4(wv, m42[k4]); pa3 += dot4(wv, m43[k4]);
      }
      float bp = p.bpred[tid];
      float4 ep2;
      {
        float tg0 = uc ? s_l[0][tid] : s_sil[0][tid - 128];
        float tg1 = uc ? s_l[1][tid] : s_sil[1][tid - 128];
        float tg2 = uc ? s_l[2][tid] : s_sil[2][tid - 128];
        float tg3 = uc ? s_l[3][tid] : s_sil[3][tid - 128];
        float e0 = pa0 + bp - tg0, e1 = pa1 + bp - tg1;
        float e2 = pa2 + bp - tg2, e3 = pa3 + bp - tg3;
        ep2 = make_float4(e0*e0, e1*e1, e2*e2, e3*e3);
      }
      float4 LP = block_sum4(ep2, s_r4);

      float o0 = uc ? s_u[0][tid] : s_l[0][tid - 128];
      float o1 = uc ? s_u[1][tid] : s_l[1][tid - 128];
      float o2 = uc ? s_u[2][tid] : s_l[2][tid - 128];
      float o3 = uc ? s_u[3][tid] : s_l[3][tid - 128];
      float q0 = n0 - o0, q1 = n1 - o1, q2 = n2 - o2, q3 = n3 - o3;
      float4 LE = block_sum4(make_float4(q0*q0, q1*q1, q2*q2, q3*q3), s_r4);

      if (tid >= b0 && tid < b1) {
        float lp = (tid == 0) ? LP.x : (tid == 1) ? LP.y : (tid == 2) ? LP.z : LP.w;
        float le = (tid == 0) ? LE.x : (tid == 1) ? LE.y : (tid == 2) ? LE.z : LE.w;
        p.loss_ev[base + tid] = lp * (1.f / 256.f) + le * (1.f / 128.f);
      }
    };

    if (!internal) {
      SPIN(0, nev);
      PROCESS(0, nev);
    } else {
      for (int e = 0; e < nev; ++e) {
        SPIN(e, e + 1);
        PROCESS(e, e + 1);
      }
    }
  }

  // ---- copy phase: ticket-based, nontemporal (keep weights L2-resident) ----
  const int ntiles = (p.N + TROWS - 1) / TROWS;
  const f32x4* src = (const f32x4*)p.emb_in;
  f32x4* dst = (f32x4*)p.emb;
  for (;;) {
    if (tid == 0) s_tile = atomicAdd(p.ticket, 1);
    __syncthreads();
    int tile = s_tile;
    __syncthreads();
    if (tile >= ntiles) break;
    int r0 = tile * TROWS;
    int nrow = min(TROWS, p.N - r0);
    if (nrow == TROWS) {
      #pragma unroll 4
      for (int k = 0; k < TROWS * 32 / NT; ++k) {
        int idx = tid + k * NT;
        int row = r0 + (idx >> 5);
        int fl = (row < NUSER) ? p.flag_u[row] : p.flag_l[row - NUSER];
        if (!fl) {
          size_t g = (size_t)row * 32 + (idx & 31);
          __builtin_nontemporal_store(__builtin_nontemporal_load(src + g), dst + g);
        }
      }
    } else {
      for (int idx = tid; idx < nrow * 32; idx += NT) {
        int row = r0 + (idx >> 5);
        int fl = (row < NUSER) ? p.flag_u[row] : p.flag_l[row - NUSER];
        if (!fl) {
          size_t g = (size_t)row * 32 + (idx & 31);
          __builtin_nontemporal_store(__builtin_nontemporal_load(src + g), dst + g);
        }
      }
    }
  }
}

__global__ void k_fin(Params p) {
  __shared__ float4 s_r4[4];
  float v = 0.f;
  for (int i = threadIdx.x; i < p.E; i += NT) v += p.loss_ev[i];
  float4 r = block_sum4(make_float4(v, 0.f, 0.f, 0.f), s_r4);
  if (threadIdx.x == 0) p.loss_slot[0] = r.x;
}

extern "C" void kernel_launch(void* const* d_in, const int* in_sizes, int n_in,
                              void* d_out, int out_size, void* d_ws, size_t ws_size,
                              hipStream_t stream) {
  Params p;
  p.emb_in = (const float*)d_in[0];
  p.stat   = (const float*)d_in[1];
  p.kg     = (const float*)d_in[2];
  p.Wihu = (const float*)d_in[3];   p.bihu = (const float*)d_in[4];
  p.Whhu = (const float*)d_in[5];   p.bhhu = (const float*)d_in[6];
  p.Wihl = (const float*)d_in[7];   p.bihl = (const float*)d_in[8];
  p.Whhl = (const float*)d_in[9];   p.bhhl = (const float*)d_in[10];
  p.wproj = (const float*)d_in[11]; p.bproj = (const float*)d_in[12];
  p.lng  = (const float*)d_in[13];  p.lnb  = (const float*)d_in[14];
  p.Wpred = (const float*)d_in[15]; p.bpred = (const float*)d_in[16];
  p.deltau = (const float*)d_in[17];
  p.deltal = (const float*)d_in[18];
  p.idxu = (const int*)d_in[19];
  p.idxl = (const int*)d_in[20];
  p.idxp = (const int*)d_in[21];
  p.idxk = (const int*)d_in[22];

  p.E    = in_sizes[17];
  p.N    = in_sizes[0] / D;
  p.NLOC = p.N - NUSER;
  p.NWORK = (p.E + CH - 1) / CH;

  p.emb       = (float*)d_out;
  p.loss_slot = (float*)d_out + (size_t)p.N * D;

  char* ws = (char*)d_ws;
  size_t off = 0;
  auto take = [&](size_t bytes) {
    void* r = ws + off;
    off += (bytes + 255) & ~(size_t)255;
    return r;
  };
  p.WpredT  = (float*)take((size_t)KP4 * 256 * 16);
  p.WrnnT   = (float*)take((size_t)KR4 * 256 * 16);
  p.brnn    = (float*)take(256 * 4);
  p.wcol    = (float*)take(256 * 4);
  p.loss_ev = (float*)take((size_t)p.E * 4);
  size_t z0 = off;
  p.cnt_u   = (int*)take((size_t)NUSER * 4);
  p.cnt_w   = (int*)take((size_t)p.NLOC * 4);
  p.cnt_t   = (int*)take((size_t)p.NLOC * 4);
  p.flag_u  = (int*)take((size_t)NUSER * 4);
  p.flag_l  = (int*)take((size_t)p.NLOC * 4);
  p.ticket  = (int*)take(256);
  size_t zbytes = off - z0;

  hipMemsetAsync(ws + z0, 0, zbytes, stream);
  hipLaunchKernelGGL(k_init, dim3(512), dim3(NT), 0, stream, p);
  hipLaunchKernelGGL(k_main, dim3(p.NWORK), dim3(NT), 0, stream, p);
  hipLaunchKernelGGL(k_fin,  dim3(1),   dim3(NT), 0, stream, p);
}

// Round 8
// 173.751 us; speedup vs baseline: 2.0131x; 1.0822x over previous
//
#include <hip/hip_runtime.h>

#define DEVINL static __device__ __forceinline__

typedef float f32x4 __attribute__((ext_vector_type(4)));

constexpr int NUSER = 100000;
constexpr int D     = 128;
constexpr int METAN = 640;
constexpr int NT    = 256;
constexpr int CH    = 4;      // events per worker block (chunk)
constexpr int KP4   = 160;    // W_pred K in float4 (640/4)
constexpr int KR4   = 96;     // RNN combined K in float4 (384/4), segment-aligned
constexpr int NCPY  = 2048;   // copy blocks (8/CU)

struct Params {
  const float *emb_in, *stat, *kg;
  const float *Wihu, *bihu, *Whhu, *bhhu;
  const float *Wihl, *bihl, *Whhl, *bhhl;
  const float *wproj, *bproj, *lng, *lnb, *Wpred, *bpred;
  const float *deltau, *deltal;
  const int *idxu, *idxl, *idxp, *idxk;
  float *emb;        // d_out [N*D]
  float *loss_slot;  // d_out + N*D
  float *WpredT;     // ws [160][256] float4
  float *WrnnT;      // ws [96][256] float4 (k: [other(128)|kg(128)|own(128)])
  float *brnn;       // ws [256]  (bih+bhh)
  float *wcol;       // ws [256]  (Wih[:,256] = delta column)
  float *loss_ev;    // ws [E]
  int *cnt_u, *cnt_w, *cnt_t;
  int *flag_u, *flag_l;
  int E, N, NLOC, NWORK;
};

DEVINL float loadx(const float* p) {
  return __hip_atomic_load(p, __ATOMIC_RELAXED, __HIP_MEMORY_SCOPE_AGENT);
}
DEVINL void storex(float* p, float v) {
  __hip_atomic_store(p, v, __ATOMIC_RELAXED, __HIP_MEMORY_SCOPE_AGENT);
}
DEVINL int loadcnt(const int* p) {
  return __hip_atomic_load(p, __ATOMIC_RELAXED, __HIP_MEMORY_SCOPE_AGENT);
}
DEVINL void sigadd(int* pp) {
  __hip_atomic_fetch_add(pp, 1, __ATOMIC_RELAXED, __HIP_MEMORY_SCOPE_AGENT);
}
DEVINL float dot4(float4 a, float4 b) { return a.x*b.x + a.y*b.y + a.z*b.z + a.w*b.w; }

DEVINL float4 block_sum4(float4 v, float4* s4) {
  #pragma unroll
  for (int o = 32; o; o >>= 1) {
    v.x += __shfl_xor(v.x, o, 64); v.y += __shfl_xor(v.y, o, 64);
    v.z += __shfl_xor(v.z, o, 64); v.w += __shfl_xor(v.w, o, 64);
  }
  if ((threadIdx.x & 63) == 0) s4[threadIdx.x >> 6] = v;
  __syncthreads();
  float4 r;
  r.x = s4[0].x + s4[1].x + s4[2].x + s4[3].x;
  r.y = s4[0].y + s4[1].y + s4[2].y + s4[3].y;
  r.z = s4[0].z + s4[1].z + s4[2].z + s4[3].z;
  r.w = s4[0].w + s4[1].w + s4[2].w + s4[3].w;
  __syncthreads();
  return r;
}

// per-wave-pair sums: {sum over tid<128, sum over tid>=128}
DEVINL void half_sum4(float4 v, float4* s4, float4* lo, float4* hi) {
  #pragma unroll
  for (int o = 32; o; o >>= 1) {
    v.x += __shfl_xor(v.x, o, 64); v.y += __shfl_xor(v.y, o, 64);
    v.z += __shfl_xor(v.z, o, 64); v.w += __shfl_xor(v.w, o, 64);
  }
  if ((threadIdx.x & 63) == 0) s4[threadIdx.x >> 6] = v;
  __syncthreads();
  lo->x = s4[0].x + s4[1].x; lo->y = s4[0].y + s4[1].y;
  lo->z = s4[0].z + s4[1].z; lo->w = s4[0].w + s4[1].w;
  hi->x = s4[2].x + s4[3].x; hi->y = s4[2].y + s4[3].y;
  hi->z = s4[2].z + s4[3].z; hi->w = s4[2].w + s4[3].w;
  __syncthreads();
}

__global__ void k_init(Params p) {
  int tid = blockIdx.x * NT + threadIdx.x;
  int stride = gridDim.x * NT;
  for (int e = tid; e < p.E; e += stride) {
    p.flag_u[p.idxu[e]] = 1;
    p.flag_l[p.idxl[e]] = 1;
  }
  for (int idx = tid; idx < 256 * KP4; idx += stride) {
    int j = idx / KP4, k4 = idx - j * KP4;
    float4 v = *(const float4*)(p.Wpred + (size_t)j * METAN + k4 * 4);
    ((float4*)p.WpredT)[k4 * 256 + j] = v;
  }
  for (int idx = tid; idx < 256 * KR4; idx += stride) {
    int j = idx / KR4, k4 = idx - j * KR4;
    int i = j & 127;
    const float* Wih = (j < 128) ? p.Wihu : p.Wihl;
    const float* Whh = (j < 128) ? p.Whhu : p.Whhl;
    float4 v; float* vp = (float*)&v;
    #pragma unroll
    for (int e = 0; e < 4; ++e) {
      int k = k4 * 4 + e;
      vp[e] = (k < 256) ? Wih[(size_t)i * 257 + k] : Whh[(size_t)i * 128 + (k - 256)];
    }
    ((float4*)p.WrnnT)[k4 * 256 + j] = v;
  }
  for (int j = tid; j < 256; j += stride) {
    int i = j & 127;
    p.brnn[j] = (j < 128) ? p.bihu[i] + p.bhhu[i] : p.bihl[i] + p.bhhl[i];
    p.wcol[j] = (j < 128) ? p.Wihu[(size_t)i * 257 + 256] : p.Wihl[(size_t)i * 257 + 256];
  }
}

// pure copy of never-written rows; measured as its own dispatch
__global__ __launch_bounds__(NT) void k_copy(Params p) {
  size_t gid = (size_t)blockIdx.x * NT + threadIdx.x;
  size_t gs  = (size_t)gridDim.x * NT;
  size_t n4  = (size_t)p.N * 32;
  const f32x4* src = (const f32x4*)p.emb_in;
  f32x4* dst = (f32x4*)p.emb;
  size_t g = gid;
  for (; g + 3 * gs < n4; g += 4 * gs) {
    size_t g0 = g, g1 = g + gs, g2 = g + 2 * gs, g3 = g + 3 * gs;
    int r0 = (int)(g0 >> 5), r1 = (int)(g1 >> 5), r2 = (int)(g2 >> 5), r3 = (int)(g3 >> 5);
    int f0 = (r0 < NUSER) ? p.flag_u[r0] : p.flag_l[r0 - NUSER];
    int f1 = (r1 < NUSER) ? p.flag_u[r1] : p.flag_l[r1 - NUSER];
    int f2 = (r2 < NUSER) ? p.flag_u[r2] : p.flag_l[r2 - NUSER];
    int f3 = (r3 < NUSER) ? p.flag_u[r3] : p.flag_l[r3 - NUSER];
    f32x4 v0 = src[g0], v1 = src[g1], v2 = src[g2], v3 = src[g3];
    if (!f0) dst[g0] = v0;
    if (!f1) dst[g1] = v1;
    if (!f2) dst[g2] = v2;
    if (!f3) dst[g3] = v3;
  }
  for (; g < n4; g += gs) {
    int r = (int)(g >> 5);
    int f = (r < NUSER) ? p.flag_u[r] : p.flag_l[r - NUSER];
    f32x4 v = src[g];
    if (!f) dst[g] = v;
  }
}

__global__ __launch_bounds__(NT, 2) void k_events(Params p) {
  __shared__ __align__(16) float s_meta[CH][METAN];
  __shared__ __align__(16) float s_u[CH][D], s_l[CH][D], s_p[CH][D], s_kg[CH][D], s_sil[CH][D];
  __shared__ float4 s_r4[4];
  __shared__ unsigned long long s_redu[4][CH];
  __shared__ int s_ev[8][CH];     // 0:iu 1:il 2:ip 3:A 4:WL 5:B 6:C 7:ik
  __shared__ float s_dd[2][CH];

  const int tid = threadIdx.x, w = tid >> 6, lane = tid & 63;

  const int base = blockIdx.x * CH;
  const int nev  = min(CH, p.E - base);
  if (nev <= 0) return;

  int iu_[CH], il_[CH], ip_[CH], ik_[CH];
  float du_[CH], dl_[CH];
  #pragma unroll
  for (int e = 0; e < CH; ++e) {
    int t = base + e; bool v = e < nev;
    iu_[e] = v ? p.idxu[t] : -1;
    il_[e] = v ? p.idxl[t] : -1;
    ip_[e] = v ? p.idxp[t] : -1;
    ik_[e] = v ? p.idxk[t] : 0;
    du_[e] = v ? p.deltau[t] : 0.f;
    dl_[e] = v ? p.deltal[t] : 0.f;
  }

  // ---- dependency counts over events s < base ----
  unsigned long long pk[CH] = {0ull,0ull,0ull,0ull};
  for (int s = tid; s < base; s += NT) {
    int ius = p.idxu[s], ils = p.idxl[s], ips = p.idxp[s];
    #pragma unroll
    for (int e = 0; e < CH; ++e) {
      unsigned long long a  = (ius == iu_[e]);
      unsigned long long wl = (ils == il_[e]);
      unsigned long long b  = (unsigned long long)((ils == il_[e]) + (ips == il_[e]));
      unsigned long long c  = (ils == ip_[e]);
      pk[e] += a | (wl << 16) | (b << 32) | (c << 48);
    }
  }
  #pragma unroll
  for (int o = 32; o; o >>= 1) {
    #pragma unroll
    for (int e = 0; e < CH; ++e) pk[e] += __shfl_xor(pk[e], o, 64);
  }
  if (lane == 0) {
    #pragma unroll
    for (int e = 0; e < CH; ++e) s_redu[w][e] = pk[e];
  }
  __syncthreads();
  #pragma unroll
  for (int e = 0; e < CH; ++e)
    pk[e] = s_redu[0][e] + s_redu[1][e] + s_redu[2][e] + s_redu[3][e];
  __syncthreads();

  int A_[CH], WL_[CH], B_[CH], C_[CH];
  #pragma unroll
  for (int e = 0; e < CH; ++e) {
    int a  = (int)(pk[e] & 0xffff),        wl = (int)((pk[e] >> 16) & 0xffff);
    int b  = (int)((pk[e] >> 32) & 0xffff), c = (int)((pk[e] >> 48) & 0xffff);
    #pragma unroll
    for (int s2 = 0; s2 < CH; ++s2) if (s2 < e) {
      a  += (iu_[s2] == iu_[e]);
      wl += (il_[s2] == il_[e]);
      b  += (il_[s2] == il_[e]) + (ip_[s2] == il_[e]);
      c  += (il_[s2] == ip_[e]);
    }
    A_[e] = a; WL_[e] = wl; B_[e] = b; C_[e] = c;
  }
  bool internal = false;
  #pragma unroll
  for (int t2 = 1; t2 < CH; ++t2) if (t2 < nev) {
    #pragma unroll
    for (int s2 = 0; s2 < t2; ++s2)
      internal |= (iu_[s2] == iu_[t2]) | (il_[s2] == il_[t2]) |
                  (il_[s2] == ip_[t2]) | (ip_[s2] == il_[t2]);
  }

  if (tid == 0) {
    #pragma unroll
    for (int e = 0; e < CH; ++e) {
      s_ev[0][e] = iu_[e]; s_ev[1][e] = il_[e]; s_ev[2][e] = ip_[e];
      s_ev[3][e] = A_[e];  s_ev[4][e] = WL_[e]; s_ev[5][e] = B_[e];
      s_ev[6][e] = C_[e];  s_ev[7][e] = ik_[e];
      s_dd[0][e] = du_[e]; s_dd[1][e] = dl_[e];
    }
  }
  __syncthreads();

  // ---- PRELOAD (before spin): kg/static always; emb rows only if first-touch ----
  auto PRELOAD = [&](int b0, int b1) {
    int e = w;
    if (e >= b0 && e < b1) {
      int iu = s_ev[0][e], ilr = s_ev[1][e] + NUSER, ipr = s_ev[2][e] + NUSER;
      int A = s_ev[3][e], WL = s_ev[4][e], Ck = s_ev[6][e], ik = s_ev[7][e];
      int h2 = lane >> 5, li = (lane & 31) * 4;
      if (h2 == 0) {
        *(float4*)&s_kg[e][li]         = *(const float4*)(p.kg   + (size_t)ik  * D + li);
        *(float4*)&s_meta[e][512 + li] = *(const float4*)(p.stat + (size_t)iu  * D + li);
      } else {
        *(float4*)&s_meta[e][384 + li] = *(const float4*)(p.stat + (size_t)ipr * D + li);
        *(float4*)&s_sil[e][li]        = *(const float4*)(p.stat + (size_t)ilr * D + li);
      }
      int i0 = lane * 2;
      if (!A) {
        *(float2*)&s_u[e][i0] = *(const float2*)(p.emb_in + (size_t)iu * D + i0);
      }
      if (!WL) {
        *(float2*)&s_l[e][i0] = *(const float2*)(p.emb_in + (size_t)ilr * D + i0);
      }
      if (!Ck) {
        *(float2*)&s_p[e][i0] = *(const float2*)(p.emb_in + (size_t)ipr * D + i0);
      }
    }
  };

  auto SPIN = [&](int b0, int b1) {
    if (w == 0) {
      int e = b0 + lane;
      bool act = lane < (b1 - b0);
      int iu = 0, il = 0, ip = 0, A = 0, Bc = 0, Cc = 0;
      if (act) {
        iu = s_ev[0][e]; il = s_ev[1][e]; ip = s_ev[2][e];
        A = s_ev[3][e]; Bc = s_ev[5][e]; Cc = s_ev[6][e];
      }
      int guard = 0;
      while (true) {
        // three INDEPENDENT loads (no short-circuit serialization)
        int x = loadcnt(&p.cnt_u[iu]);
        int y = loadcnt(&p.cnt_t[il]);
        int z = loadcnt(&p.cnt_w[ip]);
        bool ok = (!act) | ((x >= A) & (y >= Bc) & (z >= Cc));
        if (__all(ok)) break;
        if (++guard > (1 << 22)) break;   // safety valve
        __builtin_amdgcn_s_sleep(1);
      }
    }
    __syncthreads();
  };

  // ---- POSTLOAD (after spin): only rows with predecessors, agent-scope ----
  auto POSTLOAD = [&](int b0, int b1) {
    int e = w;
    if (e >= b0 && e < b1) {
      int iu = s_ev[0][e], ilr = s_ev[1][e] + NUSER, ipr = s_ev[2][e] + NUSER;
      int A = s_ev[3][e], WL = s_ev[4][e], Ck = s_ev[6][e];
      int i0 = lane * 2;
      if (A) {
        s_u[e][i0]   = loadx(p.emb + (size_t)iu * D + i0);
        s_u[e][i0+1] = loadx(p.emb + (size_t)iu * D + i0 + 1);
      }
      if (WL) {
        s_l[e][i0]   = loadx(p.emb + (size_t)ilr * D + i0);
        s_l[e][i0+1] = loadx(p.emb + (size_t)ilr * D + i0 + 1);
      }
      if (Ck) {
        s_p[e][i0]   = loadx(p.emb + (size_t)ipr * D + i0);
        s_p[e][i0+1] = loadx(p.emb + (size_t)ipr * D + i0 + 1);
      }
    }
  };

  auto PROCESS = [&](int b0, int b1) {
    __syncthreads();   // POSTLOAD LDS writes visible

    // ---- phase 2 (CRITICAL PATH): RNN matvec -> normalize -> store -> signal ----
    const bool uc = (tid < 128);
    const float4* xo0 = (const float4*)(uc ? s_l[0] : s_u[0]);
    const float4* xo1 = (const float4*)(uc ? s_l[1] : s_u[1]);
    const float4* xo2 = (const float4*)(uc ? s_l[2] : s_u[2]);
    const float4* xo3 = (const float4*)(uc ? s_l[3] : s_u[3]);
    const float4* xk0 = (const float4*)s_kg[0];
    const float4* xk1 = (const float4*)s_kg[1];
    const float4* xk2 = (const float4*)s_kg[2];
    const float4* xk3 = (const float4*)s_kg[3];
    const float4* xs0 = (const float4*)(uc ? s_u[0] : s_l[0]);
    const float4* xs1 = (const float4*)(uc ? s_u[1] : s_l[1]);
    const float4* xs2 = (const float4*)(uc ? s_u[2] : s_l[2]);
    const float4* xs3 = (const float4*)(uc ? s_u[3] : s_l[3]);
    float ra0 = 0.f, ra1 = 0.f, ra2 = 0.f, ra3 = 0.f;
    const float4* wr = (const float4*)p.WrnnT + tid;
    #pragma unroll 8
    for (int k4 = 0; k4 < 32; ++k4) {
      float4 wv = wr[k4 * 256];
      ra0 += dot4(wv, xo0[k4]); ra1 += dot4(wv, xo1[k4]);
      ra2 += dot4(wv, xo2[k4]); ra3 += dot4(wv, xo3[k4]);
    }
    #pragma unroll 8
    for (int k4 = 32; k4 < 64; ++k4) {
      float4 wv = wr[k4 * 256];
      ra0 += dot4(wv, xk0[k4-32]); ra1 += dot4(wv, xk1[k4-32]);
      ra2 += dot4(wv, xk2[k4-32]); ra3 += dot4(wv, xk3[k4-32]);
    }
    #pragma unroll 8
    for (int k4 = 64; k4 < 96; ++k4) {
      float4 wv = wr[k4 * 256];
      ra0 += dot4(wv, xs0[k4-64]); ra1 += dot4(wv, xs1[k4-64]);
      ra2 += dot4(wv, xs2[k4-64]); ra3 += dot4(wv, xs3[k4-64]);
    }
    float brn = p.brnn[tid], wcv = p.wcol[tid];
    float d0 = uc ? s_dd[0][0] : s_dd[1][0];
    float d1 = uc ? s_dd[0][1] : s_dd[1][1];
    float d2 = uc ? s_dd[0][2] : s_dd[1][2];
    float d3 = uc ? s_dd[0][3] : s_dd[1][3];
    float h0 = tanhf(ra0 + brn + wcv * d0), h1 = tanhf(ra1 + brn + wcv * d1);
    float h2v = tanhf(ra2 + brn + wcv * d2), h3 = tanhf(ra3 + brn + wcv * d3);

    float4 SU, SL;
    half_sum4(make_float4(h0*h0, h1*h1, h2v*h2v, h3*h3), s_r4, &SU, &SL);
    float s0 = uc ? SU.x : SL.x, s1 = uc ? SU.y : SL.y;
    float s2 = uc ? SU.z : SL.z, s3 = uc ? SU.w : SL.w;
    float n0 = h0 / fmaxf(sqrtf(s0), 1e-12f), n1 = h1 / fmaxf(sqrtf(s1), 1e-12f);
    float n2 = h2v / fmaxf(sqrtf(s2), 1e-12f), n3 = h3 / fmaxf(sqrtf(s3), 1e-12f);

    float nv[CH] = {n0, n1, n2, n3};
    #pragma unroll
    for (int e = 0; e < CH; ++e) if (e >= b0 && e < b1) {
      if (tid < 128) storex(p.emb + (size_t)s_ev[0][e] * D + tid, nv[e]);
      else           storex(p.emb + ((size_t)s_ev[1][e] + NUSER) * D + (tid - 128), nv[e]);
    }
    __syncthreads();   // drains vmcnt(0): stores visible at coherence point

    if (tid >= b0 && tid < b1) {
      __builtin_amdgcn_fence(__ATOMIC_RELEASE, "agent");
      sigadd(&p.cnt_u[s_ev[0][tid]]);   // SIGNAL — successors released here
      sigadd(&p.cnt_t[s_ev[1][tid]]);
      sigadd(&p.cnt_w[s_ev[1][tid]]);
      sigadd(&p.cnt_t[s_ev[2][tid]]);
    }

    // ---- phase 3 (off-chain): LN + proj + pred + losses ----
    {
      int e = w;
      if (e >= b0 && e < b1) {
        float du = s_dd[0][e];
        float4 xv = (lane < 32) ? *(const float4*)&s_p[e][lane * 4]
                                : *(const float4*)&s_kg[e][(lane - 32) * 4];
        float sm = xv.x + xv.y + xv.z + xv.w;
        #pragma unroll
        for (int o = 32; o; o >>= 1) sm += __shfl_xor(sm, o, 64);
        float mu = sm * (1.f / 256.f);
        float4 d = make_float4(xv.x - mu, xv.y - mu, xv.z - mu, xv.w - mu);
        float vs = d.x*d.x + d.y*d.y + d.z*d.z + d.w*d.w;
        #pragma unroll
        for (int o = 32; o; o >>= 1) vs += __shfl_xor(vs, o, 64);
        float rstd = rsqrtf(vs * (1.f / 256.f) + 1e-5f);
        int idx = lane * 4;
        float4 g  = *(const float4*)&p.lng[idx];
        float4 bb = *(const float4*)&p.lnb[idx];
        *(float4*)&s_meta[e][128 + idx] = make_float4(
          d.x*rstd*g.x + bb.x, d.y*rstd*g.y + bb.y,
          d.z*rstd*g.z + bb.z, d.w*rstd*g.w + bb.w);

        int i0 = lane * 2;
        #pragma unroll
        for (int j = 0; j < 2; ++j) {
          int i = i0 + j;
          s_meta[e][i] = s_u[e][i] * (1.f + p.wproj[i] * du + p.bproj[i]);
        }
      }
    }
    __syncthreads();

    const float4* m40 = (const float4*)&s_meta[0][0];
    const float4* m41 = (const float4*)&s_meta[1][0];
    const float4* m42 = (const float4*)&s_meta[2][0];
    const float4* m43 = (const float4*)&s_meta[3][0];
    float pa0 = 0.f, pa1 = 0.f, pa2 = 0.f, pa3 = 0.f;
    const float4* wp = (const float4*)p.WpredT + tid;
    #pragma unroll 8
    for (int k4 = 0; k4 < KP4; ++k4) {
      float4 wv = wp[k4 * 256];
      pa0 += dot4(wv, m40[k4]); pa1 += dot4(wv, m41[k4]);
      pa2 += dot4(wv, m42[k4]); pa3 += dot4(wv, m43[k4]);
    }
    float bp = p.bpred[tid];
    float4 ep2;
    {
      float tg0 = uc ? s_l[0][tid] : s_sil[0][tid - 128];
      float tg1 = uc ? s_l[1][tid] : s_sil[1][tid - 128];
      float tg2 = uc ? s_l[2][tid] : s_sil[2][tid - 128];
      float tg3 = uc ? s_l[3][tid] : s_sil[3][tid - 128];
      float e0 = pa0 + bp - tg0, e1 = pa1 + bp - tg1;
      float e2 = pa2 + bp - tg2, e3 = pa3 + bp - tg3;
      ep2 = make_float4(e0*e0, e1*e1, e2*e2, e3*e3);
    }
    float4 LP = block_sum4(ep2, s_r4);

    float o0 = uc ? s_u[0][tid] : s_l[0][tid - 128];
    float o1 = uc ? s_u[1][tid] : s_l[1][tid - 128];
    float o2 = uc ? s_u[2][tid] : s_l[2][tid - 128];
    float o3 = uc ? s_u[3][tid] : s_l[3][tid - 128];
    float q0 = n0 - o0, q1 = n1 - o1, q2 = n2 - o2, q3 = n3 - o3;
    float4 LE = block_sum4(make_float4(q0*q0, q1*q1, q2*q2, q3*q3), s_r4);

    if (tid >= b0 && tid < b1) {
      float lp = (tid == 0) ? LP.x : (tid == 1) ? LP.y : (tid == 2) ? LP.z : LP.w;
      float le = (tid == 0) ? LE.x : (tid == 1) ? LE.y : (tid == 2) ? LE.z : LE.w;
      p.loss_ev[base + tid] = lp * (1.f / 256.f) + le * (1.f / 128.f);
    }
  };

  if (!internal) {
    PRELOAD(0, nev);
    SPIN(0, nev);
    POSTLOAD(0, nev);
    PROCESS(0, nev);
  } else {
    for (int e = 0; e < nev; ++e) {
      PRELOAD(e, e + 1);
      SPIN(e, e + 1);
      POSTLOAD(e, e + 1);
      PROCESS(e, e + 1);
    }
  }
}

__global__ void k_fin(Params p) {
  __shared__ float4 s_r4[4];
  float v = 0.f;
  for (int i = threadIdx.x; i < p.E; i += NT) v += p.loss_ev[i];
  float4 r = block_sum4(make_float4(v, 0.f, 0.f, 0.f), s_r4);
  if (threadIdx.x == 0) p.loss_slot[0] = r.x;
}

extern "C" void kernel_launch(void* const* d_in, const int* in_sizes, int n_in,
                              void* d_out, int out_size, void* d_ws, size_t ws_size,
                              hipStream_t stream) {
  Params p;
  p.emb_in = (const float*)d_in[0];
  p.stat   = (const float*)d_in[1];
  p.kg     = (const float*)d_in[2];
  p.Wihu = (const float*)d_in[3];   p.bihu = (const float*)d_in[4];
  p.Whhu = (const float*)d_in[5];   p.bhhu = (const float*)d_in[6];
  p.Wihl = (const float*)d_in[7];   p.bihl = (const float*)d_in[8];
  p.Whhl = (const float*)d_in[9];   p.bhhl = (const float*)d_in[10];
  p.wproj = (const float*)d_in[11]; p.bproj = (const float*)d_in[12];
  p.lng  = (const float*)d_in[13];  p.lnb  = (const float*)d_in[14];
  p.Wpred = (const float*)d_in[15]; p.bpred = (const float*)d_in[16];
  p.deltau = (const float*)d_in[17];
  p.deltal = (const float*)d_in[18];
  p.idxu = (const int*)d_in[19];
  p.idxl = (const int*)d_in[20];
  p.idxp = (const int*)d_in[21];
  p.idxk = (const int*)d_in[22];

  p.E    = in_sizes[17];
  p.N    = in_sizes[0] / D;
  p.NLOC = p.N - NUSER;
  p.NWORK = (p.E + CH - 1) / CH;

  p.emb       = (float*)d_out;
  p.loss_slot = (float*)d_out + (size_t)p.N * D;

  char* ws = (char*)d_ws;
  size_t off = 0;
  auto take = [&](size_t bytes) {
    void* r = ws + off;
    off += (bytes + 255) & ~(size_t)255;
    return r;
  };
  p.WpredT  = (float*)take((size_t)KP4 * 256 * 16);
  p.WrnnT   = (float*)take((size_t)KR4 * 256 * 16);
  p.brnn    = (float*)take(256 * 4);
  p.wcol    = (float*)take(256 * 4);
  p.loss_ev = (float*)take((size_t)p.E * 4);
  size_t z0 = off;
  p.cnt_u   = (int*)take((size_t)NUSER * 4);
  p.cnt_w   = (int*)take((size_t)p.NLOC * 4);
  p.cnt_t   = (int*)take((size_t)p.NLOC * 4);
  p.flag_u  = (int*)take((size_t)NUSER * 4);
  p.flag_l  = (int*)take((size_t)p.NLOC * 4);
  size_t zbytes = off - z0;

  hipMemsetAsync(ws + z0, 0, zbytes, stream);
  hipLaunchKernelGGL(k_init,   dim3(512),    dim3(NT), 0, stream, p);
  hipLaunchKernelGGL(k_copy,   dim3(NCPY),   dim3(NT), 0, stream, p);
  hipLaunchKernelGGL(k_events, dim3(p.NWORK),dim3(NT), 0, stream, p);
  hipLaunchKernelGGL(k_fin,    dim3(1),      dim3(NT), 0, stream, p);
}

// Round 9
// 144.134 us; speedup vs baseline: 2.4268x; 1.2055x over previous
//
#include <hip/hip_runtime.h>

#define DEVINL static __device__ __forceinline__

typedef float f32x4 __attribute__((ext_vector_type(4)));

constexpr int NUSER = 100000;
constexpr int D     = 128;
constexpr int METAN = 640;
constexpr int NT    = 256;
constexpr int CH    = 4;      // events per chunk
constexpr int KP4   = 160;    // W_pred K in float4
constexpr int KR4   = 96;     // RNN combined K in float4 (384/4)
constexpr int NCPY  = 1024;   // copy blocks
constexpr int STW   = 640;    // stash floats per event: [u|l|p|nu|nl]

struct Params {
  const float *emb_in, *stat, *kg;
  const float *Wihu, *bihu, *Whhu, *bhhu;
  const float *Wihl, *bihl, *Whhl, *bhhl;
  const float *wproj, *bproj, *lng, *lnb, *Wpred, *bpred;
  const float *deltau, *deltal;
  const int *idxu, *idxl, *idxp, *idxk;
  float *emb;        // d_out [N*D]
  float *loss_slot;  // d_out + N*D
  float *WpredT;     // ws [160][256] float4
  float *WrnnT;      // ws [96][256] float4
  float *brnn;       // ws [256]
  float *wcol;       // ws [256]
  float *loss_ev;    // ws [E]
  float *stash;      // ws [E][640]
  int *cnt_u, *cnt_w, *cnt_t;
  int *flag_u, *flag_l;
  int *done;         // ws [NWORK] per-chunk stash-ready flag
  int E, N, NLOC, NWORK;
};

DEVINL float loadx(const float* p) {
  return __hip_atomic_load(p, __ATOMIC_RELAXED, __HIP_MEMORY_SCOPE_AGENT);
}
DEVINL void storex(float* p, float v) {
  __hip_atomic_store(p, v, __ATOMIC_RELAXED, __HIP_MEMORY_SCOPE_AGENT);
}
DEVINL int loadcnt(const int* p) {
  return __hip_atomic_load(p, __ATOMIC_RELAXED, __HIP_MEMORY_SCOPE_AGENT);
}
DEVINL void storei(int* p, int v) {
  __hip_atomic_store(p, v, __ATOMIC_RELAXED, __HIP_MEMORY_SCOPE_AGENT);
}
DEVINL void sigadd(int* pp) {
  __hip_atomic_fetch_add(pp, 1, __ATOMIC_RELAXED, __HIP_MEMORY_SCOPE_AGENT);
}
DEVINL float dot4(float4 a, float4 b) { return a.x*b.x + a.y*b.y + a.z*b.z + a.w*b.w; }

DEVINL float4 block_sum4(float4 v, float4* s4) {
  #pragma unroll
  for (int o = 32; o; o >>= 1) {
    v.x += __shfl_xor(v.x, o, 64); v.y += __shfl_xor(v.y, o, 64);
    v.z += __shfl_xor(v.z, o, 64); v.w += __shfl_xor(v.w, o, 64);
  }
  if ((threadIdx.x & 63) == 0) s4[threadIdx.x >> 6] = v;
  __syncthreads();
  float4 r;
  r.x = s4[0].x + s4[1].x + s4[2].x + s4[3].x;
  r.y = s4[0].y + s4[1].y + s4[2].y + s4[3].y;
  r.z = s4[0].z + s4[1].z + s4[2].z + s4[3].z;
  r.w = s4[0].w + s4[1].w + s4[2].w + s4[3].w;
  __syncthreads();
  return r;
}

DEVINL void half_sum4(float4 v, float4* s4, float4* lo, float4* hi) {
  #pragma unroll
  for (int o = 32; o; o >>= 1) {
    v.x += __shfl_xor(v.x, o, 64); v.y += __shfl_xor(v.y, o, 64);
    v.z += __shfl_xor(v.z, o, 64); v.w += __shfl_xor(v.w, o, 64);
  }
  if ((threadIdx.x & 63) == 0) s4[threadIdx.x >> 6] = v;
  __syncthreads();
  lo->x = s4[0].x + s4[1].x; lo->y = s4[0].y + s4[1].y;
  lo->z = s4[0].z + s4[1].z; lo->w = s4[0].w + s4[1].w;
  hi->x = s4[2].x + s4[3].x; hi->y = s4[2].y + s4[3].y;
  hi->z = s4[2].z + s4[3].z; hi->w = s4[2].w + s4[3].w;
  __syncthreads();
}

__global__ void k_init(Params p) {
  int tid = blockIdx.x * NT + threadIdx.x;
  int stride = gridDim.x * NT;
  for (int e = tid; e < p.E; e += stride) {
    p.flag_u[p.idxu[e]] = 1;
    p.flag_l[p.idxl[e]] = 1;
  }
  for (int idx = tid; idx < 256 * KP4; idx += stride) {
    int j = idx / KP4, k4 = idx - j * KP4;
    float4 v = *(const float4*)(p.Wpred + (size_t)j * METAN + k4 * 4);
    ((float4*)p.WpredT)[k4 * 256 + j] = v;
  }
  for (int idx = tid; idx < 256 * KR4; idx += stride) {
    int j = idx / KR4, k4 = idx - j * KR4;
    int i = j & 127;
    const float* Wih = (j < 128) ? p.Wihu : p.Wihl;
    const float* Whh = (j < 128) ? p.Whhu : p.Whhl;
    float4 v; float* vp = (float*)&v;
    #pragma unroll
    for (int e = 0; e < 4; ++e) {
      int k = k4 * 4 + e;
      vp[e] = (k < 256) ? Wih[(size_t)i * 257 + k] : Whh[(size_t)i * 128 + (k - 256)];
    }
    ((float4*)p.WrnnT)[k4 * 256 + j] = v;
  }
  for (int j = tid; j < 256; j += stride) {
    int i = j & 127;
    p.brnn[j] = (j < 128) ? p.bihu[i] + p.bhhu[i] : p.bihl[i] + p.bhhl[i];
    p.wcol[j] = (j < 128) ? p.Wihu[(size_t)i * 257 + 256] : p.Wihl[(size_t)i * 257 + 256];
  }
}

__global__ __launch_bounds__(NT, 2) void k_main(Params p) {
  __shared__ __align__(16) float s_meta[CH][METAN];
  __shared__ __align__(16) float s_u[CH][D], s_l[CH][D], s_p[CH][D], s_kg[CH][D], s_sil[CH][D];
  __shared__ float4 s_r4[4];
  __shared__ unsigned long long s_redu[4][CH];
  __shared__ int s_ev[8][CH];
  __shared__ float s_dd[2][CH];

  const int tid = threadIdx.x, w = tid >> 6, lane = tid & 63;
  const int bid = blockIdx.x;

  // ================= COPY path =================
  if (bid >= p.NWORK && bid < p.NWORK + NCPY) {
    size_t gid = (size_t)(bid - p.NWORK) * NT + tid;
    size_t gs  = (size_t)NCPY * NT;
    size_t n4  = (size_t)p.N * 32;
    const f32x4* src = (const f32x4*)p.emb_in;
    f32x4* dst = (f32x4*)p.emb;
    size_t g = gid;
    for (; g + 3 * gs < n4; g += 4 * gs) {
      size_t g0 = g, g1 = g + gs, g2 = g + 2 * gs, g3 = g + 3 * gs;
      int r0 = (int)(g0 >> 5), r1 = (int)(g1 >> 5), r2 = (int)(g2 >> 5), r3 = (int)(g3 >> 5);
      int f0 = (r0 < NUSER) ? p.flag_u[r0] : p.flag_l[r0 - NUSER];
      int f1 = (r1 < NUSER) ? p.flag_u[r1] : p.flag_l[r1 - NUSER];
      int f2 = (r2 < NUSER) ? p.flag_u[r2] : p.flag_l[r2 - NUSER];
      int f3 = (r3 < NUSER) ? p.flag_u[r3] : p.flag_l[r3 - NUSER];
      f32x4 v0 = src[g0], v1 = src[g1], v2 = src[g2], v3 = src[g3];
      if (!f0) dst[g0] = v0;
      if (!f1) dst[g1] = v1;
      if (!f2) dst[g2] = v2;
      if (!f3) dst[g3] = v3;
    }
    for (; g < n4; g += gs) {
      int r = (int)(g >> 5);
      int f = (r < NUSER) ? p.flag_u[r] : p.flag_l[r - NUSER];
      f32x4 v = src[g];
      if (!f) dst[g] = v;
    }
    return;
  }

  const bool is_chain = (bid < p.NWORK);
  const int c = is_chain ? bid : bid - p.NWORK - NCPY;
  const int base = c * CH;
  const int nev = min(CH, p.E - base);
  if (nev <= 0) return;

  int iu_[CH], il_[CH], ip_[CH], ik_[CH];
  #pragma unroll
  for (int e = 0; e < CH; ++e) {
    int t = base + e; bool v = e < nev;
    iu_[e] = v ? p.idxu[t] : -1;
    il_[e] = v ? p.idxl[t] : -1;
    ip_[e] = v ? p.idxp[t] : -1;
    ik_[e] = v ? p.idxk[t] : 0;
  }

  // ================= CHAIN path =================
  if (is_chain) {
    float du_[CH], dl_[CH];
    #pragma unroll
    for (int e = 0; e < CH; ++e) {
      int t = base + e; bool v = e < nev;
      du_[e] = v ? p.deltau[t] : 0.f;
      dl_[e] = v ? p.deltal[t] : 0.f;
    }

    unsigned long long pk[CH] = {0ull,0ull,0ull,0ull};
    for (int s = tid; s < base; s += NT) {
      int ius = p.idxu[s], ils = p.idxl[s], ips = p.idxp[s];
      #pragma unroll
      for (int e = 0; e < CH; ++e) {
        unsigned long long a  = (ius == iu_[e]);
        unsigned long long wl = (ils == il_[e]);
        unsigned long long b  = (unsigned long long)((ils == il_[e]) + (ips == il_[e]));
        unsigned long long cc = (ils == ip_[e]);
        pk[e] += a | (wl << 16) | (b << 32) | (cc << 48);
      }
    }
    #pragma unroll
    for (int o = 32; o; o >>= 1) {
      #pragma unroll
      for (int e = 0; e < CH; ++e) pk[e] += __shfl_xor(pk[e], o, 64);
    }
    if (lane == 0) {
      #pragma unroll
      for (int e = 0; e < CH; ++e) s_redu[w][e] = pk[e];
    }
    __syncthreads();
    #pragma unroll
    for (int e = 0; e < CH; ++e)
      pk[e] = s_redu[0][e] + s_redu[1][e] + s_redu[2][e] + s_redu[3][e];
    __syncthreads();

    int A_[CH], WL_[CH], B_[CH], C_[CH];
    #pragma unroll
    for (int e = 0; e < CH; ++e) {
      int a  = (int)(pk[e] & 0xffff),        wl = (int)((pk[e] >> 16) & 0xffff);
      int b  = (int)((pk[e] >> 32) & 0xffff), cc = (int)((pk[e] >> 48) & 0xffff);
      #pragma unroll
      for (int s2 = 0; s2 < CH; ++s2) if (s2 < e) {
        a  += (iu_[s2] == iu_[e]);
        wl += (il_[s2] == il_[e]);
        b  += (il_[s2] == il_[e]) + (ip_[s2] == il_[e]);
        cc += (il_[s2] == ip_[e]);
      }
      A_[e] = a; WL_[e] = wl; B_[e] = b; C_[e] = cc;
    }
    bool internal = false;
    #pragma unroll
    for (int t2 = 1; t2 < CH; ++t2) if (t2 < nev) {
      #pragma unroll
      for (int s2 = 0; s2 < t2; ++s2)
        internal |= (iu_[s2] == iu_[t2]) | (il_[s2] == il_[t2]) |
                    (il_[s2] == ip_[t2]) | (ip_[s2] == il_[t2]);
    }

    if (tid == 0) {
      #pragma unroll
      for (int e = 0; e < CH; ++e) {
        s_ev[0][e] = iu_[e]; s_ev[1][e] = il_[e]; s_ev[2][e] = ip_[e];
        s_ev[3][e] = A_[e];  s_ev[4][e] = WL_[e]; s_ev[5][e] = B_[e];
        s_ev[6][e] = C_[e];  s_ev[7][e] = ik_[e];
        s_dd[0][e] = du_[e]; s_dd[1][e] = dl_[e];
      }
    }
    __syncthreads();

    auto PRELOAD = [&](int b0, int b1) {
      int e = w;
      if (e >= b0 && e < b1) {
        int iu = s_ev[0][e], ilr = s_ev[1][e] + NUSER, ipr = s_ev[2][e] + NUSER;
        int A = s_ev[3][e], WL = s_ev[4][e], Ck = s_ev[6][e], ik = s_ev[7][e];
        if (lane < 32) {
          int li = lane * 4;
          *(float4*)&s_kg[e][li] = *(const float4*)(p.kg + (size_t)ik * D + li);
        }
        int i0 = lane * 2;
        if (!A)  *(float2*)&s_u[e][i0] = *(const float2*)(p.emb_in + (size_t)iu  * D + i0);
        if (!WL) *(float2*)&s_l[e][i0] = *(const float2*)(p.emb_in + (size_t)ilr * D + i0);
        if (!Ck) *(float2*)&s_p[e][i0] = *(const float2*)(p.emb_in + (size_t)ipr * D + i0);
      }
    };

    auto SPIN = [&](int b0, int b1) {
      if (w == 0) {
        int e = b0 + lane;
        bool act = lane < (b1 - b0);
        int iu = 0, il = 0, ip = 0, A = 0, Bc = 0, Cc = 0;
        if (act) {
          iu = s_ev[0][e]; il = s_ev[1][e]; ip = s_ev[2][e];
          A = s_ev[3][e]; Bc = s_ev[5][e]; Cc = s_ev[6][e];
        }
        int guard = 0;
        while (true) {
          int x = loadcnt(&p.cnt_u[iu]);
          int y = loadcnt(&p.cnt_t[il]);
          int z = loadcnt(&p.cnt_w[ip]);
          bool ok = (!act) | ((x >= A) & (y >= Bc) & (z >= Cc));
          if (__all(ok)) break;
          if (++guard > (1 << 22)) break;
          __builtin_amdgcn_s_sleep(1);
        }
      }
      __syncthreads();
    };

    auto POSTLOAD = [&](int b0, int b1) {
      int e = w;
      if (e >= b0 && e < b1) {
        int iu = s_ev[0][e], ilr = s_ev[1][e] + NUSER, ipr = s_ev[2][e] + NUSER;
        int A = s_ev[3][e], WL = s_ev[4][e], Ck = s_ev[6][e];
        int i0 = lane * 2;
        if (A) {
          s_u[e][i0]   = loadx(p.emb + (size_t)iu * D + i0);
          s_u[e][i0+1] = loadx(p.emb + (size_t)iu * D + i0 + 1);
        }
        if (WL) {
          s_l[e][i0]   = loadx(p.emb + (size_t)ilr * D + i0);
          s_l[e][i0+1] = loadx(p.emb + (size_t)ilr * D + i0 + 1);
        }
        if (Ck) {
          s_p[e][i0]   = loadx(p.emb + (size_t)ipr * D + i0);
          s_p[e][i0+1] = loadx(p.emb + (size_t)ipr * D + i0 + 1);
        }
      }
    };

    auto RNNPROC = [&](int b0, int b1) {
      __syncthreads();
      const bool uc = (tid < 128);
      const float4* xo0 = (const float4*)(uc ? s_l[0] : s_u[0]);
      const float4* xo1 = (const float4*)(uc ? s_l[1] : s_u[1]);
      const float4* xo2 = (const float4*)(uc ? s_l[2] : s_u[2]);
      const float4* xo3 = (const float4*)(uc ? s_l[3] : s_u[3]);
      const float4* xk0 = (const float4*)s_kg[0];
      const float4* xk1 = (const float4*)s_kg[1];
      const float4* xk2 = (const float4*)s_kg[2];
      const float4* xk3 = (const float4*)s_kg[3];
      const float4* xs0 = (const float4*)(uc ? s_u[0] : s_l[0]);
      const float4* xs1 = (const float4*)(uc ? s_u[1] : s_l[1]);
      const float4* xs2 = (const float4*)(uc ? s_u[2] : s_l[2]);
      const float4* xs3 = (const float4*)(uc ? s_u[3] : s_l[3]);
      float ra0 = 0.f, ra1 = 0.f, ra2 = 0.f, ra3 = 0.f;
      const float4* wr = (const float4*)p.WrnnT + tid;
      #pragma unroll 8
      for (int k4 = 0; k4 < 32; ++k4) {
        float4 wv = wr[k4 * 256];
        ra0 += dot4(wv, xo0[k4]); ra1 += dot4(wv, xo1[k4]);
        ra2 += dot4(wv, xo2[k4]); ra3 += dot4(wv, xo3[k4]);
      }
      #pragma unroll 8
      for (int k4 = 32; k4 < 64; ++k4) {
        float4 wv = wr[k4 * 256];
        ra0 += dot4(wv, xk0[k4-32]); ra1 += dot4(wv, xk1[k4-32]);
        ra2 += dot4(wv, xk2[k4-32]); ra3 += dot4(wv, xk3[k4-32]);
      }
      #pragma unroll 8
      for (int k4 = 64; k4 < 96; ++k4) {
        float4 wv = wr[k4 * 256];
        ra0 += dot4(wv, xs0[k4-64]); ra1 += dot4(wv, xs1[k4-64]);
        ra2 += dot4(wv, xs2[k4-64]); ra3 += dot4(wv, xs3[k4-64]);
      }
      float brn = p.brnn[tid], wcv = p.wcol[tid];
      float d0 = uc ? s_dd[0][0] : s_dd[1][0];
      float d1 = uc ? s_dd[0][1] : s_dd[1][1];
      float d2 = uc ? s_dd[0][2] : s_dd[1][2];
      float d3 = uc ? s_dd[0][3] : s_dd[1][3];
      float h0 = tanhf(ra0 + brn + wcv * d0), h1 = tanhf(ra1 + brn + wcv * d1);
      float h2v = tanhf(ra2 + brn + wcv * d2), h3 = tanhf(ra3 + brn + wcv * d3);

      float4 SU, SL;
      half_sum4(make_float4(h0*h0, h1*h1, h2v*h2v, h3*h3), s_r4, &SU, &SL);
      float s0 = uc ? SU.x : SL.x, s1 = uc ? SU.y : SL.y;
      float s2 = uc ? SU.z : SL.z, s3 = uc ? SU.w : SL.w;
      float n0 = h0 / fmaxf(sqrtf(s0), 1e-12f), n1 = h1 / fmaxf(sqrtf(s1), 1e-12f);
      float n2 = h2v / fmaxf(sqrtf(s2), 1e-12f), n3 = h3 / fmaxf(sqrtf(s3), 1e-12f);

      float nv[CH] = {n0, n1, n2, n3};
      #pragma unroll
      for (int e = 0; e < CH; ++e) if (e >= b0 && e < b1) {
        if (tid < 128) storex(p.emb + (size_t)s_ev[0][e] * D + tid, nv[e]);
        else           storex(p.emb + ((size_t)s_ev[1][e] + NUSER) * D + (tid - 128), nv[e]);
      }
      __syncthreads();   // drain row stores

      if (tid >= b0 && tid < b1) {
        __builtin_amdgcn_fence(__ATOMIC_RELEASE, "agent");
        sigadd(&p.cnt_u[s_ev[0][tid]]);   // SIGNAL (earliest possible)
        sigadd(&p.cnt_t[s_ev[1][tid]]);
        sigadd(&p.cnt_w[s_ev[1][tid]]);
        sigadd(&p.cnt_t[s_ev[2][tid]]);
      }

      // stash for loss blocks (off chain)
      #pragma unroll
      for (int e = 0; e < CH; ++e) if (e >= b0 && e < b1) {
        float* st = p.stash + (size_t)(base + e) * STW;
        if (tid < 128) {
          storex(st + tid,       s_u[e][tid]);
          storex(st + 256 + tid, s_p[e][tid]);
          storex(st + 384 + tid, nv[e]);
        } else {
          int i = tid - 128;
          storex(st + 128 + i, s_l[e][i]);
          storex(st + 512 + i, nv[e]);
        }
      }
    };

    if (!internal) {
      PRELOAD(0, nev);
      SPIN(0, nev);
      POSTLOAD(0, nev);
      RNNPROC(0, nev);
    } else {
      for (int e = 0; e < nev; ++e) {
        PRELOAD(e, e + 1);
        SPIN(e, e + 1);
        POSTLOAD(e, e + 1);
        RNNPROC(e, e + 1);
      }
    }
    __syncthreads();   // drain stash stores
    if (tid == 0) storei(&p.done[c], 1);
    return;
  }

  // ================= LOSS path =================
  {
    if (w == 0) {
      int guard = 0;
      while (!loadcnt(&p.done[c])) {
        if (++guard > (1 << 22)) break;
        __builtin_amdgcn_s_sleep(1);
      }
    }
    __syncthreads();

    // stage stash + immutable rows into LDS; wave e handles event e
    if (w < nev) {
      int e = w;
      const float* st = p.stash + (size_t)(base + e) * STW;
      int iu = iu_[e], ilr = il_[e] + NUSER, ipr = ip_[e] + NUSER, ik = ik_[e];
      int i0 = lane * 2;
      s_u[e][i0]   = loadx(st + i0);
      s_u[e][i0+1] = loadx(st + i0 + 1);
      s_l[e][i0]   = loadx(st + 128 + i0);
      s_l[e][i0+1] = loadx(st + 128 + i0 + 1);
      s_p[e][i0]   = loadx(st + 256 + i0);
      s_p[e][i0+1] = loadx(st + 256 + i0 + 1);
      int h2 = lane >> 5, li = (lane & 31) * 4;
      if (h2 == 0) {
        *(float4*)&s_kg[e][li]         = *(const float4*)(p.kg   + (size_t)ik  * D + li);
        *(float4*)&s_meta[e][512 + li] = *(const float4*)(p.stat + (size_t)iu  * D + li);
      } else {
        *(float4*)&s_meta[e][384 + li] = *(const float4*)(p.stat + (size_t)ipr * D + li);
        *(float4*)&s_sil[e][li]        = *(const float4*)(p.stat + (size_t)ilr * D + li);
      }
    }
    __syncthreads();

    // LN + proj into s_meta (wave-local per event)
    if (w < nev) {
      int e = w;
      float du = p.deltau[base + e];
      float4 xv = (lane < 32) ? *(const float4*)&s_p[e][lane * 4]
                              : *(const float4*)&s_kg[e][(lane - 32) * 4];
      float sm = xv.x + xv.y + xv.z + xv.w;
      #pragma unroll
      for (int o = 32; o; o >>= 1) sm += __shfl_xor(sm, o, 64);
      float mu = sm * (1.f / 256.f);
      float4 d = make_float4(xv.x - mu, xv.y - mu, xv.z - mu, xv.w - mu);
      float vs = d.x*d.x + d.y*d.y + d.z*d.z + d.w*d.w;
      #pragma unroll
      for (int o = 32; o; o >>= 1) vs += __shfl_xor(vs, o, 64);
      float rstd = rsqrtf(vs * (1.f / 256.f) + 1e-5f);
      int idx2 = lane * 4;
      float4 g  = *(const float4*)&p.lng[idx2];
      float4 bb = *(const float4*)&p.lnb[idx2];
      float4 lnv = make_float4(d.x*rstd*g.x + bb.x, d.y*rstd*g.y + bb.y,
                               d.z*rstd*g.z + bb.z, d.w*rstd*g.w + bb.w);
      if (lane < 32) *(float4*)&s_meta[e][128 + idx2] = lnv;
      else           *(float4*)&s_meta[e][128 + idx2] = lnv;
      int i0 = lane * 2;
      #pragma unroll
      for (int j = 0; j < 2; ++j) {
        int i = i0 + j;
        s_meta[e][i] = s_u[e][i] * (1.f + p.wproj[i] * du + p.bproj[i]);
      }
    }
    __syncthreads();

    const bool uc = (tid < 128);
    const float4* m40 = (const float4*)&s_meta[0][0];
    const float4* m41 = (const float4*)&s_meta[1][0];
    const float4* m42 = (const float4*)&s_meta[2][0];
    const float4* m43 = (const float4*)&s_meta[3][0];
    float pa0 = 0.f, pa1 = 0.f, pa2 = 0.f, pa3 = 0.f;
    const float4* wp = (const float4*)p.WpredT + tid;
    #pragma unroll 8
    for (int k4 = 0; k4 < KP4; ++k4) {
      float4 wv = wp[k4 * 256];
      pa0 += dot4(wv, m40[k4]); pa1 += dot4(wv, m41[k4]);
      pa2 += dot4(wv, m42[k4]); pa3 += dot4(wv, m43[k4]);
    }
    float bp = p.bpred[tid];
    float4 ep2;
    {
      float tg0 = uc ? s_l[0][tid] : s_sil[0][tid - 128];
      float tg1 = uc ? s_l[1][tid] : s_sil[1][tid - 128];
      float tg2 = uc ? s_l[2][tid] : s_sil[2][tid - 128];
      float tg3 = uc ? s_l[3][tid] : s_sil[3][tid - 128];
      float e0 = pa0 + bp - tg0, e1 = pa1 + bp - tg1;
      float e2 = pa2 + bp - tg2, e3 = pa3 + bp - tg3;
      ep2 = make_float4(e0*e0, e1*e1, e2*e2, e3*e3);
    }
    float4 LP = block_sum4(ep2, s_r4);

    const float* st0 = p.stash + (size_t)(base + 0) * STW;
    const float* st1 = p.stash + (size_t)(base + 1) * STW;
    const float* st2 = p.stash + (size_t)(base + 2) * STW;
    const float* st3 = p.stash + (size_t)(base + 3) * STW;
    int noff = uc ? (384 + tid) : (512 + tid - 128);
    float n0 = loadx(st0 + noff), n1 = loadx(st1 + noff);
    float n2 = loadx(st2 + noff), n3 = loadx(st3 + noff);
    float o0 = uc ? s_u[0][tid] : s_l[0][tid - 128];
    float o1 = uc ? s_u[1][tid] : s_l[1][tid - 128];
    float o2 = uc ? s_u[2][tid] : s_l[2][tid - 128];
    float o3 = uc ? s_u[3][tid] : s_l[3][tid - 128];
    float q0 = n0 - o0, q1 = n1 - o1, q2 = n2 - o2, q3 = n3 - o3;
    float4 LE = block_sum4(make_float4(q0*q0, q1*q1, q2*q2, q3*q3), s_r4);

    if (tid < nev) {
      float lp = (tid == 0) ? LP.x : (tid == 1) ? LP.y : (tid == 2) ? LP.z : LP.w;
      float le = (tid == 0) ? LE.x : (tid == 1) ? LE.y : (tid == 2) ? LE.z : LE.w;
      p.loss_ev[base + tid] = lp * (1.f / 256.f) + le * (1.f / 128.f);
    }
  }
}

__global__ void k_fin(Params p) {
  __shared__ float4 s_r4[4];
  float v = 0.f;
  for (int i = threadIdx.x; i < p.E; i += NT) v += p.loss_ev[i];
  float4 r = block_sum4(make_float4(v, 0.f, 0.f, 0.f), s_r4);
  if (threadIdx.x == 0) p.loss_slot[0] = r.x;
}

extern "C" void kernel_launch(void* const* d_in, const int* in_sizes, int n_in,
                              void* d_out, int out_size, void* d_ws, size_t ws_size,
                              hipStream_t stream) {
  Params p;
  p.emb_in = (const float*)d_in[0];
  p.stat   = (const float*)d_in[1];
  p.kg     = (const float*)d_in[2];
  p.Wihu = (const float*)d_in[3];   p.bihu = (const float*)d_in[4];
  p.Whhu = (const float*)d_in[5];   p.bhhu = (const float*)d_in[6];
  p.Wihl = (const float*)d_in[7];   p.bihl = (const float*)d_in[8];
  p.Whhl = (const float*)d_in[9];   p.bhhl = (const float*)d_in[10];
  p.wproj = (const float*)d_in[11]; p.bproj = (const float*)d_in[12];
  p.lng  = (const float*)d_in[13];  p.lnb  = (const float*)d_in[14];
  p.Wpred = (const float*)d_in[15]; p.bpred = (const float*)d_in[16];
  p.deltau = (const float*)d_in[17];
  p.deltal = (const float*)d_in[18];
  p.idxu = (const int*)d_in[19];
  p.idxl = (const int*)d_in[20];
  p.idxp = (const int*)d_in[21];
  p.idxk = (const int*)d_in[22];

  p.E    = in_sizes[17];
  p.N    = in_sizes[0] / D;
  p.NLOC = p.N - NUSER;
  p.NWORK = (p.E + CH - 1) / CH;

  p.emb       = (float*)d_out;
  p.loss_slot = (float*)d_out + (size_t)p.N * D;

  char* ws = (char*)d_ws;
  size_t off = 0;
  auto take = [&](size_t bytes) {
    void* r = ws + off;
    off += (bytes + 255) & ~(size_t)255;
    return r;
  };
  p.WpredT  = (float*)take((size_t)KP4 * 256 * 16);
  p.WrnnT   = (float*)take((size_t)KR4 * 256 * 16);
  p.brnn    = (float*)take(256 * 4);
  p.wcol    = (float*)take(256 * 4);
  p.loss_ev = (float*)take((size_t)p.E * 4);
  p.stash   = (float*)take((size_t)p.E * STW * 4);
  size_t z0 = off;
  p.cnt_u   = (int*)take((size_t)NUSER * 4);
  p.cnt_w   = (int*)take((size_t)p.NLOC * 4);
  p.cnt_t   = (int*)take((size_t)p.NLOC * 4);
  p.flag_u  = (int*)take((size_t)NUSER * 4);
  p.flag_l  = (int*)take((size_t)p.NLOC * 4);
  p.done    = (int*)take((size_t)p.NWORK * 4);
  size_t zbytes = off - z0;

  hipMemsetAsync(ws + z0, 0, zbytes, stream);
  hipLaunchKernelGGL(k_init, dim3(512), dim3(NT), 0, stream, p);
  hipLaunchKernelGGL(k_main, dim3(p.NWORK * 2 + NCPY), dim3(NT), 0, stream, p);
  hipLaunchKernelGGL(k_fin,  dim3(1),   dim3(NT), 0, stream, p);
}